// Round 28
// baseline (241.925 us; speedup 1.0000x reference)
//
#include <hip/hip_runtime.h>
#include <math.h>

// ---------------- workspace layout (floats) ----------------
#define S1SZ (768*4096)
#define FSZ  (16*1536*64)

#define OFF_FREQ 0
#define OFF_LNA  64
// bf16 buffers packed into the old lnA region (float-counted offsets)
#define OFF_WALL (OFF_LNA + 1572864)     // Wallt bf16 [1536][512]
#define OFF_WOT  (OFF_WALL + 393216)     // Wot  bf16 [512][512]
#define OFF_WQH  (OFF_WOT + 131072)      // Wqht bf16 [64][64]
#define OFF_WKH  (OFF_WQH + 2048)
#define OFF_WVH  (OFF_WKH + 2048)
#define OFF_QKV  (OFF_LNA + 6144*512)    // bf16 QKV [6144][1536] (half slot used)
#define OFF_YBUF (OFF_QKV + 6144*1536)   // bf16 ybuf [6144][512] (half slot used)
#define OFF_STATE (OFF_YBUF + 6144*512)
// stage-1 state bf16 (half of each slot used; offsets unchanged)
#define OFF_QST OFF_STATE
#define OFF_KST (OFF_QST + S1SZ)
#define OFF_VST (OFF_KST + S1SZ)
#define OFF_AST (OFF_VST + S1SZ)
// rope table float2[1536][32] -- lives in the upper (unused) half of the AST slot:
// stage-1 ast (bf16) occupies only [OFF_AST, OFF_AST + S1SZ/2); final-focus uses nothing
// above OFF_STATE + 8652288. So [OFF_AST + S1SZ/2, OFF_DP1) is dead in BOTH phases.
#define OFF_RT   (OFF_AST + S1SZ/2)
// final-focus buffers overlay the stage-1 state region (stage-1 state dead by then)
// curq/kcur/vcur/apr all bf16 (half slot used).
#define OFF_CURQ OFF_STATE
#define OFF_KCUR (OFF_CURQ + FSZ)
#define OFF_VCUR (OFF_KCUR + FSZ)
#define OFF_APR  (OFF_VCUR + FSZ)
#define OFF_QPK  (OFF_APR + FSZ)         // bf16 qpack (FSZ/2 floats)
#define OFF_KPK  (OFF_QPK + FSZ/2)
#define OFF_VPK  (OFF_KPK + FSZ/2)
#define OFF_DPF2 (OFF_VPK + FSZ/2)       // 1536 fattn diff partials
#define OFF_DP1  (OFF_STATE + 4*S1SZ)
#define OFF_DPF  (OFF_DP1 + 768)
#define OFF_FLAG (OFF_DPF + 512)
#define WS_FLOATS (OFF_FLAG + 64)

typedef __bf16 bf16x8 __attribute__((ext_vector_type(8)));
typedef __bf16 bf16x4 __attribute__((ext_vector_type(4)));
typedef __bf16 bf16x2 __attribute__((ext_vector_type(2)));
typedef float f32x4 __attribute__((ext_vector_type(4)));

// fragment-major packing: per 16-row group of a [rows][64] bf16 matrix,
// element (t,g4,l16,j) at group*1024 + (t*64 + g4*16 + l16)*8 + j.
// A wave's MFMA fragment load (16B/lane) is then lane-contiguous (1KB).

// ---------------- all weight conversions + freq + rope table in one launch ----------------
// id < 256: weight tiles; 256-258: head weights; 259: freq; 260-451: rope table
// rope[t*32+j] = {sin, cos}(t * freq_j) with arithmetic bit-identical to the old
// per-kernel sincosf path (f64 fbv -> f32 freq -> f32 mult -> sincosf).
__global__ __launch_bounds__(256) void conv_all(
    const float* __restrict__ theta_p,
    const float* __restrict__ Wq, const float* __restrict__ Wkv, const float* __restrict__ Wo,
    const float* __restrict__ Wqh, const float* __restrict__ Wkh, const float* __restrict__ Wvh,
    float* __restrict__ freq, float2* __restrict__ rope,
    __bf16* __restrict__ Wallt, __bf16* __restrict__ Wot,
    __bf16* __restrict__ Wqht, __bf16* __restrict__ Wkht, __bf16* __restrict__ Wvht) {
  int id = blockIdx.x;
  if (id >= 260) {  // rope table: 192 blocks x 256 entries
    const int gidx = (id - 260) * 256 + threadIdx.x;   // 0..49151
    const int t = gidx >> 5, j = gidx & 31;
    double stop = 2595.0 * log10(21.0);
    double ls = (j == 31) ? stop : (double)j * (stop / 31.0);
    double fbv = 200.0 * (pow(10.0, ls / 2595.0) - 1.0) / 1000.0;
    const float fj = (theta_p[0] / 220.0f) * (float)fbv;
    float sn, cs;
    sincosf((float)t * fj, &sn, &cs);
    rope[gidx] = make_float2(sn, cs);
    return;
  }
  if (id == 259) {  // freq table (f64 to match np's f64-derived fb)
    int i = threadIdx.x;
    if (i < 32) {
      double stop = 2595.0 * log10(21.0);
      double ls = (i == 31) ? stop : (double)i * (stop / 31.0);
      double fbv = 200.0 * (pow(10.0, ls / 2595.0) - 1.0) / 1000.0;
      freq[i] = (theta_p[0] / 220.0f) * (float)fbv;
    }
    return;
  }
  const float* src; __bf16* dst; int N, nt, kt;
  if (id < 64)       { src = Wq;  dst = Wallt;                     N = 512;  nt = id & 7;  kt = id >> 3; }
  else if (id < 192) { id -= 64;  src = Wkv; dst = Wallt + (size_t)512 * 512; N = 1024; nt = id & 15; kt = id >> 4; }
  else if (id < 256) { id -= 192; src = Wo;  dst = Wot;            N = 512;  nt = id & 7;  kt = id >> 3; }
  else { int t = id - 256; src = (t == 0) ? Wqh : (t == 1) ? Wkh : Wvh;
         dst = (t == 0) ? Wqht : (t == 1) ? Wkht : Wvht; N = 64; nt = 0; kt = 0; }
  const int Kd = (N == 64) ? 64 : 512;
  __shared__ float T[64][65];
  const int tid = threadIdx.x;
  const int n0 = nt * 64, k0 = kt * 64;
  for (int idx = tid; idx < 4096; idx += 256) {
    const int r = idx >> 6, c = idx & 63;
    T[r][c] = src[(size_t)(k0 + r) * N + n0 + c];
  }
  __syncthreads();
  for (int idx = tid; idx < 2048; idx += 256) {
    const int n = idx >> 5, kp = (idx & 31) << 1;
    bf16x2 pv = {(__bf16)T[kp][n], (__bf16)T[kp + 1][n]};
    *(bf16x2*)&dst[(size_t)(n0 + n) * Kd + k0 + kp] = pv;
  }
}

// ---------------- LN over 512, wave-per-row (shuffle-only, no barriers) ----------------
// f32 in -> bf16 out. Grid 1536, 4 rows/block (one per wave). rows<3072: src0, else src1.
__global__ __launch_bounds__(256) void ln512w(const float* __restrict__ src0,
                                              const float* __restrict__ src1,
                                              const float* __restrict__ g,
                                              const float* __restrict__ bb,
                                              __bf16* __restrict__ out) {
  const int tid = threadIdx.x, wv = tid >> 6, lane = tid & 63;
  const int r = blockIdx.x * 4 + wv;
  const float* src = (r < 3072) ? (src0 + (size_t)r * 512) : (src1 + (size_t)(r - 3072) * 512);
  const float4 a0 = *(const float4*)&src[lane * 8];
  const float4 a1 = *(const float4*)&src[lane * 8 + 4];
  float v[8] = {a0.x, a0.y, a0.z, a0.w, a1.x, a1.y, a1.z, a1.w};
  float sm = v[0] + v[1] + v[2] + v[3] + v[4] + v[5] + v[6] + v[7];
  sm += __shfl_xor(sm, 1);  sm += __shfl_xor(sm, 2);  sm += __shfl_xor(sm, 4);
  sm += __shfl_xor(sm, 8);  sm += __shfl_xor(sm, 16); sm += __shfl_xor(sm, 32);
  const float mean = sm * (1.f / 512.f);
  float d[8], vs = 0.f;
#pragma unroll
  for (int i = 0; i < 8; ++i) { d[i] = v[i] - mean; vs += d[i] * d[i]; }
  vs += __shfl_xor(vs, 1);  vs += __shfl_xor(vs, 2);  vs += __shfl_xor(vs, 4);
  vs += __shfl_xor(vs, 8);  vs += __shfl_xor(vs, 16); vs += __shfl_xor(vs, 32);
  const float rs = rsqrtf(vs * (1.f / 512.f) + 1e-5f);
  const float4 g0 = *(const float4*)&g[lane * 8];
  const float4 g1 = *(const float4*)&g[lane * 8 + 4];
  const float4 b0 = *(const float4*)&bb[lane * 8];
  const float4 b1 = *(const float4*)&bb[lane * 8 + 4];
  const float gg[8] = {g0.x, g0.y, g0.z, g0.w, g1.x, g1.y, g1.z, g1.w};
  const float bbv[8] = {b0.x, b0.y, b0.z, b0.w, b1.x, b1.y, b1.z, b1.w};
  bf16x8 pv;
#pragma unroll
  for (int i = 0; i < 8; ++i) pv[i] = (__bf16)(d[i] * rs * gg[i] + bbv[i]);
  *(bf16x8*)&out[(size_t)r * 512 + lane * 8] = pv;
}

// ---------------- LN over 512, wave-per-row, bf16 in -> bf16 out ([6144][512]) -------------
__global__ __launch_bounds__(256) void ln512bw(const __bf16* __restrict__ src,
                                               const float* __restrict__ g,
                                               const float* __restrict__ bb,
                                               __bf16* __restrict__ out) {
  const int tid = threadIdx.x, wv = tid >> 6, lane = tid & 63;
  const int r = blockIdx.x * 4 + wv;
  const bf16x8 sv = *(const bf16x8*)&src[(size_t)r * 512 + lane * 8];
  float v[8];
#pragma unroll
  for (int i = 0; i < 8; ++i) v[i] = (float)sv[i];
  float sm = v[0] + v[1] + v[2] + v[3] + v[4] + v[5] + v[6] + v[7];
  sm += __shfl_xor(sm, 1);  sm += __shfl_xor(sm, 2);  sm += __shfl_xor(sm, 4);
  sm += __shfl_xor(sm, 8);  sm += __shfl_xor(sm, 16); sm += __shfl_xor(sm, 32);
  const float mean = sm * (1.f / 512.f);
  float d[8], vs = 0.f;
#pragma unroll
  for (int i = 0; i < 8; ++i) { d[i] = v[i] - mean; vs += d[i] * d[i]; }
  vs += __shfl_xor(vs, 1);  vs += __shfl_xor(vs, 2);  vs += __shfl_xor(vs, 4);
  vs += __shfl_xor(vs, 8);  vs += __shfl_xor(vs, 16); vs += __shfl_xor(vs, 32);
  const float rs = rsqrtf(vs * (1.f / 512.f) + 1e-5f);
  const float4 g0 = *(const float4*)&g[lane * 8];
  const float4 g1 = *(const float4*)&g[lane * 8 + 4];
  const float4 b0 = *(const float4*)&bb[lane * 8];
  const float4 b1 = *(const float4*)&bb[lane * 8 + 4];
  const float gg[8] = {g0.x, g0.y, g0.z, g0.w, g1.x, g1.y, g1.z, g1.w};
  const float bbv[8] = {b0.x, b0.y, b0.z, b0.w, b1.x, b1.y, b1.z, b1.w};
  bf16x8 pv;
#pragma unroll
  for (int i = 0; i < 8; ++i) pv[i] = (__bf16)(d[i] * rs * gg[i] + bbv[i]);
  *(bf16x8*)&out[(size_t)r * 512 + lane * 8] = pv;
}

// ---------------- bf16 MFMA GEMM: C f32 (used for final out projection) ----------------
__global__ __launch_bounds__(256) void gemm_bf(const __bf16* __restrict__ A,
                                               const __bf16* __restrict__ Bt,
                                               float* __restrict__ C, int ldc, int K) {
  __shared__ __align__(16) __bf16 As[128][72];
  __shared__ __align__(16) __bf16 Bs[64][72];
  const int tid = threadIdx.x;
  const int wv = tid >> 6, lane = tid & 63, g4 = lane >> 4, l16 = lane & 15;
  const int m0 = blockIdx.y * 128, n0 = blockIdx.x * 64;
  f32x4 acc[2][4];
#pragma unroll
  for (int m = 0; m < 2; ++m)
#pragma unroll
    for (int n = 0; n < 4; ++n) acc[m][n] = (f32x4){0.f, 0.f, 0.f, 0.f};
  for (int k0 = 0; k0 < K; k0 += 64) {
    __syncthreads();
    for (int idx = tid; idx < 1024; idx += 256) {
      const int r = idx >> 3, c8 = (idx & 7) << 3;
      *(uint4*)&As[r][c8] = *(const uint4*)&A[(size_t)(m0 + r) * K + k0 + c8];
    }
    for (int idx = tid; idx < 512; idx += 256) {
      const int r = idx >> 3, c8 = (idx & 7) << 3;
      *(uint4*)&Bs[r][c8] = *(const uint4*)&Bt[(size_t)(n0 + r) * K + k0 + c8];
    }
    __syncthreads();
#pragma unroll
    for (int t = 0; t < 2; ++t) {
      const bf16x8 a0 = *(const bf16x8*)&As[wv * 32 + l16][t * 32 + 8 * g4];
      const bf16x8 a1 = *(const bf16x8*)&As[wv * 32 + 16 + l16][t * 32 + 8 * g4];
#pragma unroll
      for (int n = 0; n < 4; ++n) {
        const bf16x8 b = *(const bf16x8*)&Bs[n * 16 + l16][t * 32 + 8 * g4];
        acc[0][n] = __builtin_amdgcn_mfma_f32_16x16x32_bf16(a0, b, acc[0][n], 0, 0, 0);
        acc[1][n] = __builtin_amdgcn_mfma_f32_16x16x32_bf16(a1, b, acc[1][n], 0, 0, 0);
      }
    }
  }
#pragma unroll
  for (int m = 0; m < 2; ++m)
#pragma unroll
    for (int n = 0; n < 4; ++n)
#pragma unroll
      for (int j = 0; j < 4; ++j)
        C[(size_t)(m0 + wv * 32 + m * 16 + g4 * 4 + j) * ldc + n0 + n * 16 + l16] = acc[m][n][j];
}

// ---------------- bf16 MFMA GEMM: C bf16 (stage-1 QKV path) --------------
__global__ __launch_bounds__(256) void gemm_bfb(const __bf16* __restrict__ A,
                                                const __bf16* __restrict__ Bt,
                                                __bf16* __restrict__ C, int ldc, int K) {
  __shared__ __align__(16) __bf16 As[128][72];
  __shared__ __align__(16) __bf16 Bs[64][72];
  const int tid = threadIdx.x;
  const int wv = tid >> 6, lane = tid & 63, g4 = lane >> 4, l16 = lane & 15;
  const int m0 = blockIdx.y * 128, n0 = blockIdx.x * 64;
  f32x4 acc[2][4];
#pragma unroll
  for (int m = 0; m < 2; ++m)
#pragma unroll
    for (int n = 0; n < 4; ++n) acc[m][n] = (f32x4){0.f, 0.f, 0.f, 0.f};
  for (int k0 = 0; k0 < K; k0 += 64) {
    __syncthreads();
    for (int idx = tid; idx < 1024; idx += 256) {
      const int r = idx >> 3, c8 = (idx & 7) << 3;
      *(uint4*)&As[r][c8] = *(const uint4*)&A[(size_t)(m0 + r) * K + k0 + c8];
    }
    for (int idx = tid; idx < 512; idx += 256) {
      const int r = idx >> 3, c8 = (idx & 7) << 3;
      *(uint4*)&Bs[r][c8] = *(const uint4*)&Bt[(size_t)(n0 + r) * K + k0 + c8];
    }
    __syncthreads();
#pragma unroll
    for (int t = 0; t < 2; ++t) {
      const bf16x8 a0 = *(const bf16x8*)&As[wv * 32 + l16][t * 32 + 8 * g4];
      const bf16x8 a1 = *(const bf16x8*)&As[wv * 32 + 16 + l16][t * 32 + 8 * g4];
#pragma unroll
      for (int n = 0; n < 4; ++n) {
        const bf16x8 b = *(const bf16x8*)&Bs[n * 16 + l16][t * 32 + 8 * g4];
        acc[0][n] = __builtin_amdgcn_mfma_f32_16x16x32_bf16(a0, b, acc[0][n], 0, 0, 0);
        acc[1][n] = __builtin_amdgcn_mfma_f32_16x16x32_bf16(a1, b, acc[1][n], 0, 0, 0);
      }
    }
  }
#pragma unroll
  for (int m = 0; m < 2; ++m)
#pragma unroll
    for (int n = 0; n < 4; ++n)
#pragma unroll
      for (int j = 0; j < 4; ++j)
        C[(size_t)(m0 + wv * 32 + m * 16 + g4 * 4 + j) * ldc + n0 + n * 16 + l16] =
            (__bf16)acc[m][n][j];
}

// ---------------- fused final-focus QKV GEMMs (one dispatch, branch on blockIdx.x) ---------
// x<8:  q  = LN(y)  @ Wq^T  -> QKV cols [0,512)     (A rows 0..3071)
// x>=8: kv = LN(ya) @ Wkv^T -> QKV cols [512,1536)  (A rows 3072..6143)
__global__ __launch_bounds__(256) void gemm_ff(const __bf16* __restrict__ lnAb,
                                               const __bf16* __restrict__ Wallt,
                                               __bf16* __restrict__ QKV) {
  const int K = 512, ldc = 1536;
  const int nx = blockIdx.x;
  const __bf16* A; const __bf16* Bt; __bf16* C; int n0;
  if (nx < 8) { A = lnAb;                        Bt = Wallt;                        C = QKV;       n0 = nx * 64; }
  else        { A = lnAb + (size_t)3072 * 512;   Bt = Wallt + (size_t)512 * 512;    C = QKV + 512; n0 = (nx - 8) * 64; }
  __shared__ __align__(16) __bf16 As[128][72];
  __shared__ __align__(16) __bf16 Bs[64][72];
  const int tid = threadIdx.x;
  const int wv = tid >> 6, lane = tid & 63, g4 = lane >> 4, l16 = lane & 15;
  const int m0 = blockIdx.y * 128;
  f32x4 acc[2][4];
#pragma unroll
  for (int m = 0; m < 2; ++m)
#pragma unroll
    for (int n = 0; n < 4; ++n) acc[m][n] = (f32x4){0.f, 0.f, 0.f, 0.f};
  for (int k0 = 0; k0 < K; k0 += 64) {
    __syncthreads();
    for (int idx = tid; idx < 1024; idx += 256) {
      const int r = idx >> 3, c8 = (idx & 7) << 3;
      *(uint4*)&As[r][c8] = *(const uint4*)&A[(size_t)(m0 + r) * K + k0 + c8];
    }
    for (int idx = tid; idx < 512; idx += 256) {
      const int r = idx >> 3, c8 = (idx & 7) << 3;
      *(uint4*)&Bs[r][c8] = *(const uint4*)&Bt[(size_t)(n0 + r) * K + k0 + c8];
    }
    __syncthreads();
#pragma unroll
    for (int t = 0; t < 2; ++t) {
      const bf16x8 a0 = *(const bf16x8*)&As[wv * 32 + l16][t * 32 + 8 * g4];
      const bf16x8 a1 = *(const bf16x8*)&As[wv * 32 + 16 + l16][t * 32 + 8 * g4];
#pragma unroll
      for (int n = 0; n < 4; ++n) {
        const bf16x8 b = *(const bf16x8*)&Bs[n * 16 + l16][t * 32 + 8 * g4];
        acc[0][n] = __builtin_amdgcn_mfma_f32_16x16x32_bf16(a0, b, acc[0][n], 0, 0, 0);
        acc[1][n] = __builtin_amdgcn_mfma_f32_16x16x32_bf16(a1, b, acc[1][n], 0, 0, 0);
      }
    }
  }
#pragma unroll
  for (int m = 0; m < 2; ++m)
#pragma unroll
    for (int n = 0; n < 4; ++n)
#pragma unroll
      for (int j = 0; j < 4; ++j)
        C[(size_t)(m0 + wv * 32 + m * 16 + g4 * 4 + j) * ldc + n0 + n * 16 + l16] =
            (__bf16)acc[m][n][j];
}

// ---------------- shared helpers ----------------
__device__ __forceinline__ void proj64(int tid, const __bf16 (*X)[72], __bf16 (*WP)[72],
                                       const __bf16* __restrict__ Wg,
                                       const float* __restrict__ bias, f32x4 acc[4]) {
  for (int idx = tid; idx < 512; idx += 256) {
    const int r = idx >> 3, c8 = (idx & 7) << 3;
    *(uint4*)&WP[r][c8] = *(const uint4*)&Wg[r * 64 + c8];
  }
  __syncthreads();
  const int lane = tid & 63, wv = tid >> 6, g4 = lane >> 4, l16 = lane & 15;
  const bf16x8 a0 = *(const bf16x8*)&X[wv * 16 + l16][8 * g4];
  const bf16x8 a1 = *(const bf16x8*)&X[wv * 16 + l16][32 + 8 * g4];
#pragma unroll
  for (int c = 0; c < 4; ++c) {
    f32x4 z = (f32x4){0.f, 0.f, 0.f, 0.f};
    const bf16x8 b0 = *(const bf16x8*)&WP[c * 16 + l16][8 * g4];
    const bf16x8 b1 = *(const bf16x8*)&WP[c * 16 + l16][32 + 8 * g4];
    z = __builtin_amdgcn_mfma_f32_16x16x32_bf16(a0, b0, z, 0, 0, 0);
    z = __builtin_amdgcn_mfma_f32_16x16x32_bf16(a1, b1, z, 0, 0, 0);
    const float bb = bias[c * 16 + l16];
    z[0] += bb; z[1] += bb; z[2] += bb; z[3] += bb;
    acc[c] = z;
  }
  __syncthreads();   // all waves done reading WP and X -> both may be overwritten
}

__device__ __forceinline__ void lnreg(f32x4 acc[4], const float gl[4], const float bl[4]) {
#pragma unroll
  for (int j = 0; j < 4; ++j) {
    float sm = acc[0][j] + acc[1][j] + acc[2][j] + acc[3][j];
    sm += __shfl_xor(sm, 1); sm += __shfl_xor(sm, 2);
    sm += __shfl_xor(sm, 4); sm += __shfl_xor(sm, 8);
    const float m = sm * (1.f / 64.f);
    float d[4], vs = 0.f;
#pragma unroll
    for (int c = 0; c < 4; ++c) { d[c] = acc[c][j] - m; vs += d[c] * d[c]; }
    vs += __shfl_xor(vs, 1); vs += __shfl_xor(vs, 2);
    vs += __shfl_xor(vs, 4); vs += __shfl_xor(vs, 8);
    const float rs = rsqrtf(vs * (1.f / 64.f) + 1e-5f);
#pragma unroll
    for (int c = 0; c < 4; ++c) acc[c][j] = d[c] * rs * gl[c] + bl[c];
  }
}

// ---------------- stage-1 per-window focus iteration (bf16 MFMA) ----------------
// QKV is bf16 (rope math still f32, via precomputed rope table rows 0..63).
// LDS aliasing: A0 = Xq then LN'd q; A1 = Xk then LN'd k; A2 = Xv then Vt (transposed v).
__global__ __launch_bounds__(256) void focus_win(
    int it, float sscale, const __bf16* __restrict__ QKV,
    __bf16* __restrict__ qst, __bf16* __restrict__ kst, __bf16* __restrict__ vst,
    __bf16* __restrict__ ast, __bf16* __restrict__ ybuf, float* __restrict__ dpart,
    const float2* __restrict__ rope,
    const __bf16* __restrict__ Wqht, const __bf16* __restrict__ Wkht,
    const __bf16* __restrict__ Wvht,
    const float* __restrict__ bq, const float* __restrict__ bk, const float* __restrict__ bv,
    const float* __restrict__ lng, const float* __restrict__ lnb) {
  __shared__ __align__(16) __bf16 A0[64][72], A1[64][72], A2[64][72];
  __shared__ __align__(16) __bf16 WP[64][72];
  __shared__ float red[256];
  __shared__ float flagsh;
  const int tid = threadIdx.x;
  const int bid = blockIdx.x;
  const int s = bid / 384, rem = bid % 384, w = rem >> 4, bh = rem & 15;
  const int b = bh >> 3, h = bh & 7;

  if (it == 2) {
    if (tid == 0) {
      const int g = s * 24 + w;
      float sum = 0.f;
      for (int i = 0; i < 16; ++i) sum += dpart[g * 16 + i];
      flagsh = (sum * (1.f / 65536.f) < 0.5f) ? 1.f : 0.f;
    }
    __syncthreads();
    if (flagsh > 0.5f) return;
  }

  const size_t sb = (size_t)bid * 4096;
  if (it == 0) {
    const int qrow0 = s * 3072 + b * 1536 + w * 64;
    const int krow0 = s * 3072 + b * 1536 + (w == 0 ? 0 : w * 64 - 8);
    for (int idx = tid; idx < 2048; idx += 256) {
      const int r = idx >> 5, j = idx & 31;
      const float2 rc = rope[r * 32 + j];
      const float sn = rc.x, cs = rc.y;
      const bf16x2 qp = *(const bf16x2*)&QKV[(size_t)(qrow0 + r) * 1536 + h * 64 + 2 * j];
      const float qr = (float)qp[0], qi = (float)qp[1];
      const float q0 = qr * cs - qi * sn;
      const float q1 = qr * sn + qi * cs;
      const bf16x2 qv = {(__bf16)q0, (__bf16)q1};
      *(bf16x2*)&A0[r][2 * j] = qv;
      *(bf16x2*)&qst[sb + r * 64 + 2 * j] = qv;
      const bf16x2 kp2 = *(const bf16x2*)&QKV[(size_t)(krow0 + r) * 1536 + 512 + h * 64 + 2 * j];
      const float kr = (float)kp2[0], ki = (float)kp2[1];
      A1[r][2 * j]     = (__bf16)(kr * cs - ki * sn);
      A1[r][2 * j + 1] = (__bf16)(kr * sn + ki * cs);
      const bf16x2 vp2 = *(const bf16x2*)&QKV[(size_t)(krow0 + r) * 1536 + 1024 + h * 64 + 2 * j];
      A2[r][2 * j] = vp2[0]; A2[r][2 * j + 1] = vp2[1];
    }
  } else {
    for (int idx = tid; idx < 512; idx += 256) {
      const int r = idx >> 3, c8 = (idx & 7) << 3;
      *(bf16x8*)&A0[r][c8] = *(const bf16x8*)&qst[sb + (size_t)r * 64 + c8];
      *(bf16x8*)&A1[r][c8] = *(const bf16x8*)&kst[sb + (size_t)r * 64 + c8];
      *(bf16x8*)&A2[r][c8] = *(const bf16x8*)&vst[sb + (size_t)r * 64 + c8];
    }
  }
  // (barrier inside first proj64 covers the staging writes)

  const int wv = tid >> 6, lane = tid & 63, g4 = lane >> 4, l16 = lane & 15;
  const int row = wv * 16 + g4 * 4;
  float gl[4], bl[4];
#pragma unroll
  for (int c = 0; c < 4; ++c) { gl[c] = lng[c * 16 + l16]; bl[c] = lnb[c * 16 + l16]; }

  f32x4 acc[4];
  // ---- qt = LN(A0 @ Wq + bq) -> back into A0 ----
  proj64(tid, A0, WP, Wqht, bq, acc);
  lnreg(acc, gl, bl);
#pragma unroll
  for (int c = 0; c < 4; ++c)
#pragma unroll
    for (int j = 0; j < 4; ++j) A0[row + j][c * 16 + l16] = (__bf16)acc[c][j];

  // ---- kt = A1 @ Wk + bk (store raw), LN -> back into A1 ----
  proj64(tid, A1, WP, Wkht, bk, acc);
  if (it <= 1)
#pragma unroll
    for (int c = 0; c < 4; ++c)
#pragma unroll
      for (int j = 0; j < 4; ++j) kst[sb + (size_t)(row + j) * 64 + c * 16 + l16] = (__bf16)acc[c][j];
  lnreg(acc, gl, bl);
#pragma unroll
  for (int c = 0; c < 4; ++c)
#pragma unroll
    for (int j = 0; j < 4; ++j) A1[row + j][c * 16 + l16] = (__bf16)acc[c][j];

  // ---- vt = A2 @ Wv + bv (store raw), transposed -> back into A2 ----
  proj64(tid, A2, WP, Wvht, bv, acc);
  if (it <= 1)
#pragma unroll
    for (int c = 0; c < 4; ++c)
#pragma unroll
      for (int j = 0; j < 4; ++j) vst[sb + (size_t)(row + j) * 64 + c * 16 + l16] = (__bf16)acc[c][j];
#pragma unroll
  for (int c = 0; c < 4; ++c) {
    bf16x4 pv = {(__bf16)acc[c][0], (__bf16)acc[c][1], (__bf16)acc[c][2], (__bf16)acc[c][3]};
    *(bf16x4*)&A2[c * 16 + l16][row] = pv;   // Vt[d][key]
  }
  __syncthreads();   // A0/A1/A2 new roles visible to all waves

  const bf16x8 aq0 = *(const bf16x8*)&A0[wv * 16 + l16][8 * g4];
  const bf16x8 aq1 = *(const bf16x8*)&A0[wv * 16 + l16][32 + 8 * g4];
  f32x4 sreg[4];
#pragma unroll
  for (int c = 0; c < 4; ++c) {
    f32x4 z = (f32x4){0.f, 0.f, 0.f, 0.f};
    const bf16x8 b0 = *(const bf16x8*)&A1[c * 16 + l16][8 * g4];
    const bf16x8 b1 = *(const bf16x8*)&A1[c * 16 + l16][32 + 8 * g4];
    z = __builtin_amdgcn_mfma_f32_16x16x32_bf16(aq0, b0, z, 0, 0, 0);
    z = __builtin_amdgcn_mfma_f32_16x16x32_bf16(aq1, b1, z, 0, 0, 0);
    sreg[c] = z * sscale;
  }
#pragma unroll
  for (int j = 0; j < 4; ++j) {
    float mx = fmaxf(fmaxf(sreg[0][j], sreg[1][j]), fmaxf(sreg[2][j], sreg[3][j]));
    mx = fmaxf(mx, __shfl_xor(mx, 1)); mx = fmaxf(mx, __shfl_xor(mx, 2));
    mx = fmaxf(mx, __shfl_xor(mx, 4)); mx = fmaxf(mx, __shfl_xor(mx, 8));
    float ps = 0.f;
#pragma unroll
    for (int c = 0; c < 4; ++c) { const float e = expf(sreg[c][j] - mx); sreg[c][j] = e; ps += e; }
    ps += __shfl_xor(ps, 1); ps += __shfl_xor(ps, 2);
    ps += __shfl_xor(ps, 4); ps += __shfl_xor(ps, 8);
    const float inv = 1.f / ps;
#pragma unroll
    for (int c = 0; c < 4; ++c) sreg[c][j] *= inv;
  }
#pragma unroll
  for (int c = 0; c < 4; ++c)
#pragma unroll
    for (int j = 0; j < 4; ++j) WP[row + j][c * 16 + l16] = (__bf16)sreg[c][j];
  const bf16x8 pa0 = *(const bf16x8*)&WP[wv * 16 + l16][8 * g4];
  const bf16x8 pa1 = *(const bf16x8*)&WP[wv * 16 + l16][32 + 8 * g4];
  f32x4 o[4];
#pragma unroll
  for (int dt = 0; dt < 4; ++dt) {
    f32x4 z = (f32x4){0.f, 0.f, 0.f, 0.f};
    const bf16x8 b0 = *(const bf16x8*)&A2[dt * 16 + l16][8 * g4];
    const bf16x8 b1 = *(const bf16x8*)&A2[dt * 16 + l16][32 + 8 * g4];
    z = __builtin_amdgcn_mfma_f32_16x16x32_bf16(pa0, b0, z, 0, 0, 0);
    z = __builtin_amdgcn_mfma_f32_16x16x32_bf16(pa1, b1, z, 0, 0, 0);
    o[dt] = z;
  }

  if (it == 0) {
#pragma unroll
    for (int dt = 0; dt < 4; ++dt)
#pragma unroll
      for (int j = 0; j < 4; ++j) {
        const size_t gi = sb + (size_t)(row + j) * 64 + dt * 16 + l16;
        const float a = o[dt][j];
        ast[gi] = (__bf16)a;
        qst[gi] = (__bf16)((float)qst[gi] + a);
      }
  } else if (it == 1) {
    float loc = 0.f;
#pragma unroll
    for (int dt = 0; dt < 4; ++dt)
#pragma unroll
      for (int j = 0; j < 4; ++j) {
        const size_t gi = sb + (size_t)(row + j) * 64 + dt * 16 + l16;
        const float a = o[dt][j];
        loc += fabsf(a - (float)ast[gi]);
        qst[gi] = (__bf16)((float)qst[gi] + a);
        ybuf[((size_t)((s * 2 + b) * 1536 + w * 64 + row + j)) * 512 + h * 64 + dt * 16 + l16] = (__bf16)a;
      }
    red[tid] = loc;
    __syncthreads();
    for (int o2 = 128; o2; o2 >>= 1) { if (tid < o2) red[tid] += red[tid + o2]; __syncthreads(); }
    if (tid == 0) dpart[bid] = red[0];
  } else {
#pragma unroll
    for (int dt = 0; dt < 4; ++dt)
#pragma unroll
      for (int j = 0; j < 4; ++j)
        ybuf[((size_t)((s * 2 + b) * 1536 + w * 64 + row + j)) * 512 + h * 64 + dt * 16 + l16] = (__bf16)o[dt][j];
  }
}

// ---------------- final-focus projection+LN, one op per block (q/k/v split) ----------------
// Grid (384, 3): x = chunk-unit (bh fastest -> XCD-local), y = op (0=q,1=k,2=v).
// it0 rope via precomputed table (bit-identical values).
__global__ __launch_bounds__(256) void fprojv(
    int it, float sscale, const float* __restrict__ flagp,
    const __bf16* __restrict__ QKV, const float2* __restrict__ rope,
    __bf16* __restrict__ curq, __bf16* __restrict__ kcur, __bf16* __restrict__ vcur,
    __bf16* __restrict__ qpack, __bf16* __restrict__ kpack, __bf16* __restrict__ vpack,
    const __bf16* __restrict__ Wqht, const __bf16* __restrict__ Wkht,
    const __bf16* __restrict__ Wvht,
    const float* __restrict__ bq, const float* __restrict__ bk, const float* __restrict__ bv,
    const float* __restrict__ lng, const float* __restrict__ lnb) {
  if (it == 2 && flagp[0] > 0.5f) return;
  __shared__ __align__(16) __bf16 X[64][72];
  __shared__ __align__(16) __bf16 Y[64][72];
  __shared__ __align__(16) __bf16 WP[64][72];
  const int tid = threadIdx.x;
  const int u = blockIdx.x, op = blockIdx.y;
  const int bh = u & 15, chunk = u >> 4;
  const size_t base = (size_t)bh * 98304 + (size_t)chunk * 4096;   // [t][64] element region

  if (it == 0) {
    const int t0 = chunk * 64;
    const int bb2 = bh >> 3, hh = bh & 7;
    if (op == 2) {
      // v: never roped -- pure bf16 vector copy from QKV cols [1024,1536)
      for (int idx = tid; idx < 512; idx += 256) {
        const int r = idx >> 3, c8 = (idx & 7) << 3;
        *(bf16x8*)&X[r][c8] =
            *(const bf16x8*)&QKV[(size_t)(bb2 * 1536 + t0 + r) * 1536 + 1024 + hh * 64 + c8];
      }
    } else {
      const int off = (op == 0) ? 0 : 512;
      for (int idx = tid; idx < 2048; idx += 256) {
        const int r = idx >> 5, j = idx & 31;
        const int t = t0 + r;
        const __bf16* src = QKV + (size_t)(bb2 * 1536 + t) * 1536 + off;
        const float2 rc = rope[t * 32 + j];
        const float sn = rc.x, cs = rc.y;
        const bf16x2 p2 = *(const bf16x2*)&src[hh * 64 + 2 * j];
        const float xr = (float)p2[0], xi = (float)p2[1];
        const float v0 = xr * cs - xi * sn;
        const float v1 = xr * sn + xi * cs;
        const bf16x2 pv = {(__bf16)v0, (__bf16)v1};
        *(bf16x2*)&X[r][2 * j] = pv;
        if (op == 0) *(bf16x2*)&curq[base + (size_t)r * 64 + 2 * j] = pv;
      }
    }
  } else {
    const __bf16* ch = (op == 0) ? curq : (op == 1) ? kcur : vcur;
    for (int idx = tid; idx < 512; idx += 256) {
      const int r = idx >> 3, c8 = (idx & 7) << 3;
      *(bf16x8*)&X[r][c8] = *(const bf16x8*)&ch[base + (size_t)r * 64 + c8];
    }
  }
  // (proj64's internal barrier covers the staging writes)

  const int wv = tid >> 6, lane = tid & 63, g4 = lane >> 4, l16 = lane & 15;
  const int row = wv * 16 + g4 * 4;

  const __bf16* Wg = (op == 0) ? Wqht : (op == 1) ? Wkht : Wvht;
  const float* bias = (op == 0) ? bq : (op == 1) ? bk : bv;
  f32x4 acc[4];
  proj64(tid, X, WP, Wg, bias, acc);

  if (op == 0) {
    float gl[4], bl[4];
#pragma unroll
    for (int c = 0; c < 4; ++c) { gl[c] = lng[c * 16 + l16]; bl[c] = lnb[c * 16 + l16]; }
    lnreg(acc, gl, bl);
#pragma unroll
    for (int c = 0; c < 4; ++c)
#pragma unroll
      for (int j = 0; j < 4; ++j) Y[row + j][c * 16 + l16] = (__bf16)(acc[c][j] * sscale);
    __syncthreads();
#pragma unroll
    for (int ii = 0; ii < 2; ++ii) {
      const int sg = tid * 2 + ii;               // 0..511
      const int g = sg >> 7, s = sg & 127;
      const int t = s >> 6, g4p = (s >> 4) & 3, l16p = s & 15;
      bf16x8 pv = *(const bf16x8*)&Y[g * 16 + l16p][t * 32 + 8 * g4p];
      *(bf16x8*)&qpack[base + (size_t)g * 1024 + (size_t)s * 8] = pv;
    }
  } else if (op == 1) {
#pragma unroll
    for (int c = 0; c < 4; ++c)
#pragma unroll
      for (int j = 0; j < 4; ++j)
        kcur[base + (size_t)(row + j) * 64 + c * 16 + l16] = (__bf16)acc[c][j];
    float gl[4], bl[4];
#pragma unroll
    for (int c = 0; c < 4; ++c) { gl[c] = lng[c * 16 + l16]; bl[c] = lnb[c * 16 + l16]; }
    lnreg(acc, gl, bl);
#pragma unroll
    for (int c = 0; c < 4; ++c)
#pragma unroll
      for (int j = 0; j < 4; ++j) Y[row + j][c * 16 + l16] = (__bf16)acc[c][j];
    __syncthreads();
#pragma unroll
    for (int ii = 0; ii < 2; ++ii) {
      const int sg = tid * 2 + ii;
      const int g = sg >> 7, s = sg & 127;
      const int t = s >> 6, g4p = (s >> 4) & 3, l16p = s & 15;
      bf16x8 pv = *(const bf16x8*)&Y[g * 16 + l16p][t * 32 + 8 * g4p];
      *(bf16x8*)&kpack[base + (size_t)g * 1024 + (size_t)s * 8] = pv;
    }
  } else {
#pragma unroll
    for (int c = 0; c < 4; ++c)
#pragma unroll
      for (int j = 0; j < 4; ++j) {
        vcur[base + (size_t)(row + j) * 64 + c * 16 + l16] = (__bf16)acc[c][j];
        Y[row + j][c * 16 + l16] = (__bf16)acc[c][j];
      }
    __syncthreads();
#pragma unroll
    for (int ii = 0; ii < 2; ++ii) {
      const int sg = tid * 2 + ii;               // 0..511 = dt*128 + s
      const int dt = sg >> 7, s = sg & 127;
      const int t = s >> 6, g4p = (s >> 4) & 3, l16p = s & 15;
      bf16x8 pv;
#pragma unroll
      for (int j = 0; j < 8; ++j)
        pv[j] = Y[t * 32 + 8 * g4p + j][dt * 16 + l16p];
      *(bf16x8*)&vpack[base + (size_t)sg * 8] = pv;
    }
  }
}

// ---------------- final-focus flash attention: 16 q-rows/block (1 strip), 4-way k-split,
// no-max softmax. Grid 1536: bid = qc*16 + bh (96 q-chunks, bh fastest for XCD-local L2).
// (256,3): natural VGPR, no spill. Pipelined k-loop (R26). R28: fdec folded into it1 via
// atomic counter (flagp[1]) + last-block reduction; counter zeroed by it0 block 0.
__global__ __launch_bounds__(256, 3) void fattn(
    int it,
    const __bf16* __restrict__ qpack, const __bf16* __restrict__ kpack,
    const __bf16* __restrict__ vpack,
    __bf16* __restrict__ Rout, __bf16* __restrict__ aprev, __bf16* __restrict__ curq,
    float* __restrict__ dpart, float* __restrict__ flagp) {
  if (it == 2 && flagp[0] > 0.5f) return;
  __shared__ __align__(16) __bf16 Pl[4][16][72]; // per-wave P transpose strip
  __shared__ float Ob[4][16][65];                // per-wave O-numerator partials
  __shared__ float Ll[4][16];                    // per-wave l partials
  __shared__ float redm[4];
  __shared__ float red2[256];
  __shared__ unsigned lastsh;
  const int tid = threadIdx.x;
  const int wv = tid >> 6, lane = tid & 63;
  const int g4 = lane >> 4, l16 = lane & 15;
  const int bid = blockIdx.x;
  const int bh = bid & 15, qc = bid >> 4;          // qc in 0..95
  const int bb2 = bh >> 3, hh = bh & 7;            // batch, head for reorder write
  const size_t base = (size_t)bh * (1536 * 64);
  const __bf16* qp = qpack + base;
  const __bf16* kp = kpack + base;
  const __bf16* vp = vpack + base;
  const int q0 = qc * 16;

  if (it == 0 && bid == 0 && tid == 0) *(unsigned*)&flagp[1] = 0u;  // reset it1 counter

  bf16x8 aq[2];
#pragma unroll
  for (int t = 0; t < 2; ++t)
    aq[t] = *(const bf16x8*)&qp[(size_t)qc * 1024 + (size_t)(t * 64 + lane) * 8];

  f32x4 oacc[4];
#pragma unroll
  for (int dt = 0; dt < 4; ++dt) oacc[dt] = (f32x4){0.f, 0.f, 0.f, 0.f};
  float lsum[4] = {0.f, 0.f, 0.f, 0.f};

  const int kbeg = wv * 384, kend = kbeg + 384;
  // prologue: first tile's K fragments
  bf16x8 bk[4][2];
#pragma unroll
  for (int c = 0; c < 4; ++c)
#pragma unroll
    for (int t = 0; t < 2; ++t)
      bk[c][t] = *(const bf16x8*)&kp[(size_t)((kbeg >> 4) + c) * 1024 + (size_t)(t * 64 + lane) * 8];

  for (int k0 = kbeg; k0 < kend; k0 += 64) {
    // prefetch next tile's K fragments (latency hidden under this tile's compute)
    const int k1 = k0 + 64;
    bf16x8 bkn[4][2];
    if (k1 < kend) {
#pragma unroll
      for (int c = 0; c < 4; ++c)
#pragma unroll
        for (int t = 0; t < 2; ++t)
          bkn[c][t] = *(const bf16x8*)&kp[(size_t)((k1 >> 4) + c) * 1024 + (size_t)(t * 64 + lane) * 8];
    }

    // QK^T MFMAs
    f32x4 s[4];
#pragma unroll
    for (int c = 0; c < 4; ++c) {
      f32x4 a = (f32x4){0.f, 0.f, 0.f, 0.f};
      a = __builtin_amdgcn_mfma_f32_16x16x32_bf16(aq[0], bk[c][0], a, 0, 0, 0);
      a = __builtin_amdgcn_mfma_f32_16x16x32_bf16(aq[1], bk[c][1], a, 0, 0, 0);
      s[c] = a;   // Q pre-scaled by sscale
    }

    // V fragments: batch-issued so their latency hides under exp + LDS roundtrip
    bf16x8 vv[4][2];
#pragma unroll
    for (int dt = 0; dt < 4; ++dt) {
      const size_t vb = (size_t)((k0 >> 6) * 4 + dt) * 1024;
      vv[dt][0] = *(const bf16x8*)&vp[vb + (size_t)lane * 8];
      vv[dt][1] = *(const bf16x8*)&vp[vb + (size_t)(64 + lane) * 8];
    }

    // no-max softmax: p = exp(s); per-lane partial l (cross-lane reduce deferred)
#pragma unroll
    for (int c = 0; c < 4; ++c)
#pragma unroll
      for (int j = 0; j < 4; ++j) {
        const float p = __expf(s[c][j]);
        s[c][j] = p;
        lsum[j] += p;
      }
    // P C-layout -> A-layout via per-wave LDS strip
#pragma unroll
    for (int c = 0; c < 4; ++c)
#pragma unroll
      for (int j = 0; j < 4; ++j)
        Pl[wv][g4 * 4 + j][c * 16 + l16] = (__bf16)s[c][j];
    bf16x8 pa[2];
#pragma unroll
    for (int t = 0; t < 2; ++t)
      pa[t] = *(const bf16x8*)&Pl[wv][l16][t * 32 + 8 * g4];

    // PV MFMAs consume the prefetched V fragments
#pragma unroll
    for (int dt = 0; dt < 4; ++dt) {
      oacc[dt] = __builtin_amdgcn_mfma_f32_16x16x32_bf16(pa[0], vv[dt][0], oacc[dt], 0, 0, 0);
      oacc[dt] = __builtin_amdgcn_mfma_f32_16x16x32_bf16(pa[1], vv[dt][1], oacc[dt], 0, 0, 0);
    }

    if (k1 < kend) {
#pragma unroll
      for (int c = 0; c < 4; ++c) {
        bk[c][0] = bkn[c][0];
        bk[c][1] = bkn[c][1];
      }
    }
  }

  // one deferred cross-lane l reduction
#pragma unroll
  for (int j = 0; j < 4; ++j) {
    lsum[j] += __shfl_xor(lsum[j], 1);
    lsum[j] += __shfl_xor(lsum[j], 2);
    lsum[j] += __shfl_xor(lsum[j], 4);
    lsum[j] += __shfl_xor(lsum[j], 8);
  }
  if (l16 == 0) {
#pragma unroll
    for (int j = 0; j < 4; ++j) Ll[wv][g4 * 4 + j] = lsum[j];
  }
#pragma unroll
  for (int dt = 0; dt < 4; ++dt)
#pragma unroll
    for (int j = 0; j < 4; ++j)
      Ob[wv][g4 * 4 + j][dt * 16 + l16] = oacc[dt][j];
  __syncthreads();

  // merge (pure sums): each wave merges 4 rows, lane = column
  float loc = 0.f;
  const int col = lane;
#pragma unroll
  for (int rr = 0; rr < 4; ++rr) {
    const int r = wv * 4 + rr;
    const float L = Ll[0][r] + Ll[1][r] + Ll[2][r] + Ll[3][r];
    const float o = (Ob[0][r][col] + Ob[1][r][col] +
                     Ob[2][r][col] + Ob[3][r][col]) / L;
    const size_t gi = base + (size_t)(q0 + r) * 64 + col;
    if (it == 1) loc += fabsf(o - (float)aprev[gi]);
    if (it > 0)   // final output path: reordered bf16 GEMM input (a0 never final)
      Rout[(size_t)(bb2 * 1536 + q0 + r) * 512 + hh * 64 + col] = (__bf16)o;
    if (it == 0) { aprev[gi] = (__bf16)o; curq[gi] = (__bf16)((float)curq[gi] + o); }
    else if (it == 1) curq[gi] = (__bf16)((float)curq[gi] + o);  // aprev never read after it1
  }
  if (it == 1) {
    for (int o2 = 32; o2; o2 >>= 1) loc += __shfl_xor(loc, o2, 64);
    if (lane == 0) redm[wv] = loc;
    __syncthreads();
    if (tid == 0) dpart[bid] = redm[0] + redm[1] + redm[2] + redm[3];
    // folded fdec: last block to finish reduces all partials and writes the flag
    if (tid == 0) {
      __threadfence();
      const unsigned old = atomicAdd((unsigned*)&flagp[1], 1u);
      lastsh = (old == 1535u) ? 1u : 0u;
    }
    __syncthreads();
    if (lastsh) {
      float s2 = 0.f;
      for (int i = tid; i < 1536; i += 256) s2 += dpart[i];
      red2[tid] = s2;
      __syncthreads();
      for (int o2 = 128; o2; o2 >>= 1) { if (tid < o2) red2[tid] += red2[tid + o2]; __syncthreads(); }
      if (tid == 0) flagp[0] = (red2[0] * (1.f / 1572864.f) < 0.5f) ? 1.f : 0.f;
    }
  }
}

// ---------------- launch ----------------
extern "C" void kernel_launch(void* const* d_in, const int* in_sizes, int n_in,
                              void* d_out, int out_size, void* d_ws, size_t ws_size,
                              hipStream_t stream) {
  const float* x     = (const float*)d_in[0];
  const float* xa    = (const float*)d_in[1];
  const float* Wq    = (const float*)d_in[2];
  const float* Wkv   = (const float*)d_in[3];
  const float* Wo    = (const float*)d_in[4];
  const float* lna_g = (const float*)d_in[5];
  const float* lna_b = (const float*)d_in[6];
  const float* lnb_g = (const float*)d_in[7];
  const float* lnb_b = (const float*)d_in[8];
  const float* Wq_hd = (const float*)d_in[9];
  const float* bq_hd = (const float*)d_in[10];
  const float* Wk_hd = (const float*)d_in[11];
  const float* bk_hd = (const float*)d_in[12];
  const float* Wv_hd = (const float*)d_in[13];
  const float* bv_hd = (const float*)d_in[14];
  const float* theta = (const float*)d_in[15];
  float* out = (float*)d_out;
  float* ws = (float*)d_ws;
  if (ws_size < (size_t)WS_FLOATS * sizeof(float)) return;

  float* freq = ws + OFF_FREQ;
  float2* rope = (float2*)(ws + OFF_RT);
  __bf16* lnAb = (__bf16*)(ws + OFF_LNA);
  __bf16* Wallt = (__bf16*)(ws + OFF_WALL);
  __bf16* Wot  = (__bf16*)(ws + OFF_WOT);
  __bf16* Wqht = (__bf16*)(ws + OFF_WQH);
  __bf16* Wkht = (__bf16*)(ws + OFF_WKH);
  __bf16* Wvht = (__bf16*)(ws + OFF_WVH);
  __bf16* QKV = (__bf16*)(ws + OFF_QKV);
  __bf16* ybuf = (__bf16*)(ws + OFF_YBUF);
  __bf16* qst = (__bf16*)(ws + OFF_QST);
  __bf16* kst = (__bf16*)(ws + OFF_KST);
  __bf16* vst = (__bf16*)(ws + OFF_VST);
  __bf16* ast = (__bf16*)(ws + OFF_AST);
  __bf16* curq = (__bf16*)(ws + OFF_CURQ);
  __bf16* kcur = (__bf16*)(ws + OFF_KCUR);
  __bf16* vcur = (__bf16*)(ws + OFF_VCUR);
  __bf16* apr  = (__bf16*)(ws + OFF_APR);
  float* dp1  = ws + OFF_DP1;
  float* dpf2 = ws + OFF_DPF2;   // 1536 fattn diff partials
  float* flg  = ws + OFF_FLAG;   // [0]=flag, [1]=it1 completion counter
  __bf16* qpack = (__bf16*)(ws + OFF_QPK);
  __bf16* kpack = (__bf16*)(ws + OFF_KPK);
  __bf16* vpack = (__bf16*)(ws + OFF_VPK);

  const float sc[3] = {0.125f,
                       (float)(0.125 * sqrt(1.0 / 0.995)),
                       (float)(0.125 * sqrt(1.0 / 0.99))};

  conv_all<<<452, 256, 0, stream>>>(theta, Wq, Wkv, Wo, Wq_hd, Wk_hd, Wv_hd,
                                    freq, rope, Wallt, Wot, Wqht, Wkht, Wvht);

  // ---- stage 1: both slides ----
  ln512w<<<1536, 256, 0, stream>>>(x, xa, lna_g, lna_b, lnAb);
  gemm_bfb<<<dim3(24, 48), 256, 0, stream>>>(lnAb, Wallt, QKV, 1536, 512);
  for (int it = 0; it < 3; ++it)
    focus_win<<<768, 256, 0, stream>>>(it, sc[it], QKV, qst, kst, vst, ast, ybuf, dp1,
                                       rope, Wqht, Wkht, Wvht, bq_hd, bk_hd, bv_hd,
                                       lnb_g, lnb_b);

  // ---- final focus ----
  ln512bw<<<1536, 256, 0, stream>>>(ybuf, lna_g, lna_b, lnAb);
  gemm_ff<<<dim3(24, 24), 256, 0, stream>>>(lnAb, Wallt, QKV);

  for (int it = 0; it < 3; ++it) {
    fprojv<<<dim3(384, 3), 256, 0, stream>>>(it, sc[it], flg, QKV, rope, curq, kcur, vcur,
                                             qpack, kpack, vpack,
                                             Wqht, Wkht, Wvht, bq_hd, bk_hd, bv_hd,
                                             lnb_g, lnb_b);
    fattn<<<1536, 256, 0, stream>>>(it, qpack, kpack, vpack,
                                    lnAb, apr, curq, dpf2, flg);
  }

  // ---- output projection (fattn wrote reordered bf16 R directly into lnAb) ----
  gemm_bf<<<dim3(8, 24), 256, 0, stream>>>(lnAb, Wot, out, 512, 512);
}

// Round 29
// 206.893 us; speedup vs baseline: 1.1693x; 1.1693x over previous
//
#include <hip/hip_runtime.h>
#include <math.h>

// ---------------- workspace layout (floats) ----------------
#define S1SZ (768*4096)
#define FSZ  (16*1536*64)

#define OFF_FREQ 0
#define OFF_LNA  64
// bf16 buffers packed into the old lnA region (float-counted offsets)
#define OFF_WALL (OFF_LNA + 1572864)     // Wallt bf16 [1536][512]
#define OFF_WOT  (OFF_WALL + 393216)     // Wot  bf16 [512][512]
#define OFF_WQH  (OFF_WOT + 131072)      // Wqht bf16 [64][64]
#define OFF_WKH  (OFF_WQH + 2048)
#define OFF_WVH  (OFF_WKH + 2048)
#define OFF_QKV  (OFF_LNA + 6144*512)    // bf16 QKV [6144][1536] (half slot used)
#define OFF_YBUF (OFF_QKV + 6144*1536)   // bf16 ybuf [6144][512] (half slot used)
#define OFF_STATE (OFF_YBUF + 6144*512)
// stage-1 state bf16 (half of each slot used; offsets unchanged)
#define OFF_QST OFF_STATE
#define OFF_KST (OFF_QST + S1SZ)
#define OFF_VST (OFF_KST + S1SZ)
#define OFF_AST (OFF_VST + S1SZ)
// rope table float2[1536][32] -- upper (unused) half of the AST slot: stage-1 ast (bf16)
// occupies only [OFF_AST, OFF_AST + S1SZ/2); final-focus buffers end at OFF_STATE+8652288.
#define OFF_RT   (OFF_AST + S1SZ/2)
// final-focus buffers overlay the stage-1 state region (stage-1 state dead by then)
// curq/kcur/vcur/apr all bf16 (half slot used).
#define OFF_CURQ OFF_STATE
#define OFF_KCUR (OFF_CURQ + FSZ)
#define OFF_VCUR (OFF_KCUR + FSZ)
#define OFF_APR  (OFF_VCUR + FSZ)
#define OFF_QPK  (OFF_APR + FSZ)         // bf16 qpack (FSZ/2 floats)
#define OFF_KPK  (OFF_QPK + FSZ/2)
#define OFF_VPK  (OFF_KPK + FSZ/2)
#define OFF_DPF2 (OFF_VPK + FSZ/2)       // 1536 fattn diff partials
#define OFF_DP1  (OFF_STATE + 4*S1SZ)
#define OFF_DPF  (OFF_DP1 + 768)
#define OFF_FLAG (OFF_DPF + 512)
#define WS_FLOATS (OFF_FLAG + 64)

typedef __bf16 bf16x8 __attribute__((ext_vector_type(8)));
typedef __bf16 bf16x4 __attribute__((ext_vector_type(4)));
typedef __bf16 bf16x2 __attribute__((ext_vector_type(2)));
typedef float f32x4 __attribute__((ext_vector_type(4)));

// fragment-major packing: per 16-row group of a [rows][64] bf16 matrix,
// element (t,g4,l16,j) at group*1024 + (t*64 + g4*16 + l16)*8 + j.
// A wave's MFMA fragment load (16B/lane) is then lane-contiguous (1KB).

// ---------------- all weight conversions + freq + rope table in one launch ----------------
// id < 256: weight tiles; 256-258: head weights; 259: freq; 260-451: rope table
// rope[t*32+j] = {sin, cos}(t * freq_j), arithmetic bit-identical to the old per-kernel
// sincosf path (f64 fbv -> f32 freq -> f32 mult -> sincosf).
__global__ __launch_bounds__(256) void conv_all(
    const float* __restrict__ theta_p,
    const float* __restrict__ Wq, const float* __restrict__ Wkv, const float* __restrict__ Wo,
    const float* __restrict__ Wqh, const float* __restrict__ Wkh, const float* __restrict__ Wvh,
    float* __restrict__ freq, float2* __restrict__ rope,
    __bf16* __restrict__ Wallt, __bf16* __restrict__ Wot,
    __bf16* __restrict__ Wqht, __bf16* __restrict__ Wkht, __bf16* __restrict__ Wvht) {
  int id = blockIdx.x;
  if (id >= 260) {  // rope table: 192 blocks x 256 entries
    const int gidx = (id - 260) * 256 + threadIdx.x;   // 0..49151
    const int t = gidx >> 5, j = gidx & 31;
    double stop = 2595.0 * log10(21.0);
    double ls = (j == 31) ? stop : (double)j * (stop / 31.0);
    double fbv = 200.0 * (pow(10.0, ls / 2595.0) - 1.0) / 1000.0;
    const float fj = (theta_p[0] / 220.0f) * (float)fbv;
    float sn, cs;
    sincosf((float)t * fj, &sn, &cs);
    rope[gidx] = make_float2(sn, cs);
    return;
  }
  if (id == 259) {  // freq table (f64 to match np's f64-derived fb)
    int i = threadIdx.x;
    if (i < 32) {
      double stop = 2595.0 * log10(21.0);
      double ls = (i == 31) ? stop : (double)i * (stop / 31.0);
      double fbv = 200.0 * (pow(10.0, ls / 2595.0) - 1.0) / 1000.0;
      freq[i] = (theta_p[0] / 220.0f) * (float)fbv;
    }
    return;
  }
  const float* src; __bf16* dst; int N, nt, kt;
  if (id < 64)       { src = Wq;  dst = Wallt;                     N = 512;  nt = id & 7;  kt = id >> 3; }
  else if (id < 192) { id -= 64;  src = Wkv; dst = Wallt + (size_t)512 * 512; N = 1024; nt = id & 15; kt = id >> 4; }
  else if (id < 256) { id -= 192; src = Wo;  dst = Wot;            N = 512;  nt = id & 7;  kt = id >> 3; }
  else { int t = id - 256; src = (t == 0) ? Wqh : (t == 1) ? Wkh : Wvh;
         dst = (t == 0) ? Wqht : (t == 1) ? Wkht : Wvht; N = 64; nt = 0; kt = 0; }
  const int Kd = (N == 64) ? 64 : 512;
  __shared__ float T[64][65];
  const int tid = threadIdx.x;
  const int n0 = nt * 64, k0 = kt * 64;
  for (int idx = tid; idx < 4096; idx += 256) {
    const int r = idx >> 6, c = idx & 63;
    T[r][c] = src[(size_t)(k0 + r) * N + n0 + c];
  }
  __syncthreads();
  for (int idx = tid; idx < 2048; idx += 256) {
    const int n = idx >> 5, kp = (idx & 31) << 1;
    bf16x2 pv = {(__bf16)T[kp][n], (__bf16)T[kp + 1][n]};
    *(bf16x2*)&dst[(size_t)(n0 + n) * Kd + k0 + kp] = pv;
  }
}

// ---------------- LN over 512, wave-per-row (shuffle-only, no barriers) ----------------
// f32 in -> bf16 out. Grid 1536, 4 rows/block (one per wave). rows<3072: src0, else src1.
__global__ __launch_bounds__(256) void ln512w(const float* __restrict__ src0,
                                              const float* __restrict__ src1,
                                              const float* __restrict__ g,
                                              const float* __restrict__ bb,
                                              __bf16* __restrict__ out) {
  const int tid = threadIdx.x, wv = tid >> 6, lane = tid & 63;
  const int r = blockIdx.x * 4 + wv;
  const float* src = (r < 3072) ? (src0 + (size_t)r * 512) : (src1 + (size_t)(r - 3072) * 512);
  const float4 a0 = *(const float4*)&src[lane * 8];
  const float4 a1 = *(const float4*)&src[lane * 8 + 4];
  float v[8] = {a0.x, a0.y, a0.z, a0.w, a1.x, a1.y, a1.z, a1.w};
  float sm = v[0] + v[1] + v[2] + v[3] + v[4] + v[5] + v[6] + v[7];
  sm += __shfl_xor(sm, 1);  sm += __shfl_xor(sm, 2);  sm += __shfl_xor(sm, 4);
  sm += __shfl_xor(sm, 8);  sm += __shfl_xor(sm, 16); sm += __shfl_xor(sm, 32);
  const float mean = sm * (1.f / 512.f);
  float d[8], vs = 0.f;
#pragma unroll
  for (int i = 0; i < 8; ++i) { d[i] = v[i] - mean; vs += d[i] * d[i]; }
  vs += __shfl_xor(vs, 1);  vs += __shfl_xor(vs, 2);  vs += __shfl_xor(vs, 4);
  vs += __shfl_xor(vs, 8);  vs += __shfl_xor(vs, 16); vs += __shfl_xor(vs, 32);
  const float rs = rsqrtf(vs * (1.f / 512.f) + 1e-5f);
  const float4 g0 = *(const float4*)&g[lane * 8];
  const float4 g1 = *(const float4*)&g[lane * 8 + 4];
  const float4 b0 = *(const float4*)&bb[lane * 8];
  const float4 b1 = *(const float4*)&bb[lane * 8 + 4];
  const float gg[8] = {g0.x, g0.y, g0.z, g0.w, g1.x, g1.y, g1.z, g1.w};
  const float bbv[8] = {b0.x, b0.y, b0.z, b0.w, b1.x, b1.y, b1.z, b1.w};
  bf16x8 pv;
#pragma unroll
  for (int i = 0; i < 8; ++i) pv[i] = (__bf16)(d[i] * rs * gg[i] + bbv[i]);
  *(bf16x8*)&out[(size_t)r * 512 + lane * 8] = pv;
}

// ---------------- LN over 512, wave-per-row, bf16 in -> bf16 out ([6144][512]) -------------
__global__ __launch_bounds__(256) void ln512bw(const __bf16* __restrict__ src,
                                               const float* __restrict__ g,
                                               const float* __restrict__ bb,
                                               __bf16* __restrict__ out) {
  const int tid = threadIdx.x, wv = tid >> 6, lane = tid & 63;
  const int r = blockIdx.x * 4 + wv;
  const bf16x8 sv = *(const bf16x8*)&src[(size_t)r * 512 + lane * 8];
  float v[8];
#pragma unroll
  for (int i = 0; i < 8; ++i) v[i] = (float)sv[i];
  float sm = v[0] + v[1] + v[2] + v[3] + v[4] + v[5] + v[6] + v[7];
  sm += __shfl_xor(sm, 1);  sm += __shfl_xor(sm, 2);  sm += __shfl_xor(sm, 4);
  sm += __shfl_xor(sm, 8);  sm += __shfl_xor(sm, 16); sm += __shfl_xor(sm, 32);
  const float mean = sm * (1.f / 512.f);
  float d[8], vs = 0.f;
#pragma unroll
  for (int i = 0; i < 8; ++i) { d[i] = v[i] - mean; vs += d[i] * d[i]; }
  vs += __shfl_xor(vs, 1);  vs += __shfl_xor(vs, 2);  vs += __shfl_xor(vs, 4);
  vs += __shfl_xor(vs, 8);  vs += __shfl_xor(vs, 16); vs += __shfl_xor(vs, 32);
  const float rs = rsqrtf(vs * (1.f / 512.f) + 1e-5f);
  const float4 g0 = *(const float4*)&g[lane * 8];
  const float4 g1 = *(const float4*)&g[lane * 8 + 4];
  const float4 b0 = *(const float4*)&bb[lane * 8];
  const float4 b1 = *(const float4*)&bb[lane * 8 + 4];
  const float gg[8] = {g0.x, g0.y, g0.z, g0.w, g1.x, g1.y, g1.z, g1.w};
  const float bbv[8] = {b0.x, b0.y, b0.z, b0.w, b1.x, b1.y, b1.z, b1.w};
  bf16x8 pv;
#pragma unroll
  for (int i = 0; i < 8; ++i) pv[i] = (__bf16)(d[i] * rs * gg[i] + bbv[i]);
  *(bf16x8*)&out[(size_t)r * 512 + lane * 8] = pv;
}

// ---------------- bf16 MFMA GEMM: C f32 (used for final out projection) ----------------
__global__ __launch_bounds__(256) void gemm_bf(const __bf16* __restrict__ A,
                                               const __bf16* __restrict__ Bt,
                                               float* __restrict__ C, int ldc, int K) {
  __shared__ __align__(16) __bf16 As[128][72];
  __shared__ __align__(16) __bf16 Bs[64][72];
  const int tid = threadIdx.x;
  const int wv = tid >> 6, lane = tid & 63, g4 = lane >> 4, l16 = lane & 15;
  const int m0 = blockIdx.y * 128, n0 = blockIdx.x * 64;
  f32x4 acc[2][4];
#pragma unroll
  for (int m = 0; m < 2; ++m)
#pragma unroll
    for (int n = 0; n < 4; ++n) acc[m][n] = (f32x4){0.f, 0.f, 0.f, 0.f};
  for (int k0 = 0; k0 < K; k0 += 64) {
    __syncthreads();
    for (int idx = tid; idx < 1024; idx += 256) {
      const int r = idx >> 3, c8 = (idx & 7) << 3;
      *(uint4*)&As[r][c8] = *(const uint4*)&A[(size_t)(m0 + r) * K + k0 + c8];
    }
    for (int idx = tid; idx < 512; idx += 256) {
      const int r = idx >> 3, c8 = (idx & 7) << 3;
      *(uint4*)&Bs[r][c8] = *(const uint4*)&Bt[(size_t)(n0 + r) * K + k0 + c8];
    }
    __syncthreads();
#pragma unroll
    for (int t = 0; t < 2; ++t) {
      const bf16x8 a0 = *(const bf16x8*)&As[wv * 32 + l16][t * 32 + 8 * g4];
      const bf16x8 a1 = *(const bf16x8*)&As[wv * 32 + 16 + l16][t * 32 + 8 * g4];
#pragma unroll
      for (int n = 0; n < 4; ++n) {
        const bf16x8 b = *(const bf16x8*)&Bs[n * 16 + l16][t * 32 + 8 * g4];
        acc[0][n] = __builtin_amdgcn_mfma_f32_16x16x32_bf16(a0, b, acc[0][n], 0, 0, 0);
        acc[1][n] = __builtin_amdgcn_mfma_f32_16x16x32_bf16(a1, b, acc[1][n], 0, 0, 0);
      }
    }
  }
#pragma unroll
  for (int m = 0; m < 2; ++m)
#pragma unroll
    for (int n = 0; n < 4; ++n)
#pragma unroll
      for (int j = 0; j < 4; ++j)
        C[(size_t)(m0 + wv * 32 + m * 16 + g4 * 4 + j) * ldc + n0 + n * 16 + l16] = acc[m][n][j];
}

// ---------------- bf16 MFMA GEMM: C bf16 (stage-1 QKV path) --------------
__global__ __launch_bounds__(256) void gemm_bfb(const __bf16* __restrict__ A,
                                                const __bf16* __restrict__ Bt,
                                                __bf16* __restrict__ C, int ldc, int K) {
  __shared__ __align__(16) __bf16 As[128][72];
  __shared__ __align__(16) __bf16 Bs[64][72];
  const int tid = threadIdx.x;
  const int wv = tid >> 6, lane = tid & 63, g4 = lane >> 4, l16 = lane & 15;
  const int m0 = blockIdx.y * 128, n0 = blockIdx.x * 64;
  f32x4 acc[2][4];
#pragma unroll
  for (int m = 0; m < 2; ++m)
#pragma unroll
    for (int n = 0; n < 4; ++n) acc[m][n] = (f32x4){0.f, 0.f, 0.f, 0.f};
  for (int k0 = 0; k0 < K; k0 += 64) {
    __syncthreads();
    for (int idx = tid; idx < 1024; idx += 256) {
      const int r = idx >> 3, c8 = (idx & 7) << 3;
      *(uint4*)&As[r][c8] = *(const uint4*)&A[(size_t)(m0 + r) * K + k0 + c8];
    }
    for (int idx = tid; idx < 512; idx += 256) {
      const int r = idx >> 3, c8 = (idx & 7) << 3;
      *(uint4*)&Bs[r][c8] = *(const uint4*)&Bt[(size_t)(n0 + r) * K + k0 + c8];
    }
    __syncthreads();
#pragma unroll
    for (int t = 0; t < 2; ++t) {
      const bf16x8 a0 = *(const bf16x8*)&As[wv * 32 + l16][t * 32 + 8 * g4];
      const bf16x8 a1 = *(const bf16x8*)&As[wv * 32 + 16 + l16][t * 32 + 8 * g4];
#pragma unroll
      for (int n = 0; n < 4; ++n) {
        const bf16x8 b = *(const bf16x8*)&Bs[n * 16 + l16][t * 32 + 8 * g4];
        acc[0][n] = __builtin_amdgcn_mfma_f32_16x16x32_bf16(a0, b, acc[0][n], 0, 0, 0);
        acc[1][n] = __builtin_amdgcn_mfma_f32_16x16x32_bf16(a1, b, acc[1][n], 0, 0, 0);
      }
    }
  }
#pragma unroll
  for (int m = 0; m < 2; ++m)
#pragma unroll
    for (int n = 0; n < 4; ++n)
#pragma unroll
      for (int j = 0; j < 4; ++j)
        C[(size_t)(m0 + wv * 32 + m * 16 + g4 * 4 + j) * ldc + n0 + n * 16 + l16] =
            (__bf16)acc[m][n][j];
}

// ---------------- fused final-focus QKV GEMMs (one dispatch, branch on blockIdx.x) ---------
// x<8:  q  = LN(y)  @ Wq^T  -> QKV cols [0,512)     (A rows 0..3071)
// x>=8: kv = LN(ya) @ Wkv^T -> QKV cols [512,1536)  (A rows 3072..6143)
__global__ __launch_bounds__(256) void gemm_ff(const __bf16* __restrict__ lnAb,
                                               const __bf16* __restrict__ Wallt,
                                               __bf16* __restrict__ QKV) {
  const int K = 512, ldc = 1536;
  const int nx = blockIdx.x;
  const __bf16* A; const __bf16* Bt; __bf16* C; int n0;
  if (nx < 8) { A = lnAb;                        Bt = Wallt;                        C = QKV;       n0 = nx * 64; }
  else        { A = lnAb + (size_t)3072 * 512;   Bt = Wallt + (size_t)512 * 512;    C = QKV + 512; n0 = (nx - 8) * 64; }
  __shared__ __align__(16) __bf16 As[128][72];
  __shared__ __align__(16) __bf16 Bs[64][72];
  const int tid = threadIdx.x;
  const int wv = tid >> 6, lane = tid & 63, g4 = lane >> 4, l16 = lane & 15;
  const int m0 = blockIdx.y * 128;
  f32x4 acc[2][4];
#pragma unroll
  for (int m = 0; m < 2; ++m)
#pragma unroll
    for (int n = 0; n < 4; ++n) acc[m][n] = (f32x4){0.f, 0.f, 0.f, 0.f};
  for (int k0 = 0; k0 < K; k0 += 64) {
    __syncthreads();
    for (int idx = tid; idx < 1024; idx += 256) {
      const int r = idx >> 3, c8 = (idx & 7) << 3;
      *(uint4*)&As[r][c8] = *(const uint4*)&A[(size_t)(m0 + r) * K + k0 + c8];
    }
    for (int idx = tid; idx < 512; idx += 256) {
      const int r = idx >> 3, c8 = (idx & 7) << 3;
      *(uint4*)&Bs[r][c8] = *(const uint4*)&Bt[(size_t)(n0 + r) * K + k0 + c8];
    }
    __syncthreads();
#pragma unroll
    for (int t = 0; t < 2; ++t) {
      const bf16x8 a0 = *(const bf16x8*)&As[wv * 32 + l16][t * 32 + 8 * g4];
      const bf16x8 a1 = *(const bf16x8*)&As[wv * 32 + 16 + l16][t * 32 + 8 * g4];
#pragma unroll
      for (int n = 0; n < 4; ++n) {
        const bf16x8 b = *(const bf16x8*)&Bs[n * 16 + l16][t * 32 + 8 * g4];
        acc[0][n] = __builtin_amdgcn_mfma_f32_16x16x32_bf16(a0, b, acc[0][n], 0, 0, 0);
        acc[1][n] = __builtin_amdgcn_mfma_f32_16x16x32_bf16(a1, b, acc[1][n], 0, 0, 0);
      }
    }
  }
#pragma unroll
  for (int m = 0; m < 2; ++m)
#pragma unroll
    for (int n = 0; n < 4; ++n)
#pragma unroll
      for (int j = 0; j < 4; ++j)
        C[(size_t)(m0 + wv * 32 + m * 16 + g4 * 4 + j) * ldc + n0 + n * 16 + l16] =
            (__bf16)acc[m][n][j];
}

// ---------------- shared helpers ----------------
__device__ __forceinline__ void proj64(int tid, const __bf16 (*X)[72], __bf16 (*WP)[72],
                                       const __bf16* __restrict__ Wg,
                                       const float* __restrict__ bias, f32x4 acc[4]) {
  for (int idx = tid; idx < 512; idx += 256) {
    const int r = idx >> 3, c8 = (idx & 7) << 3;
    *(uint4*)&WP[r][c8] = *(const uint4*)&Wg[r * 64 + c8];
  }
  __syncthreads();
  const int lane = tid & 63, wv = tid >> 6, g4 = lane >> 4, l16 = lane & 15;
  const bf16x8 a0 = *(const bf16x8*)&X[wv * 16 + l16][8 * g4];
  const bf16x8 a1 = *(const bf16x8*)&X[wv * 16 + l16][32 + 8 * g4];
#pragma unroll
  for (int c = 0; c < 4; ++c) {
    f32x4 z = (f32x4){0.f, 0.f, 0.f, 0.f};
    const bf16x8 b0 = *(const bf16x8*)&WP[c * 16 + l16][8 * g4];
    const bf16x8 b1 = *(const bf16x8*)&WP[c * 16 + l16][32 + 8 * g4];
    z = __builtin_amdgcn_mfma_f32_16x16x32_bf16(a0, b0, z, 0, 0, 0);
    z = __builtin_amdgcn_mfma_f32_16x16x32_bf16(a1, b1, z, 0, 0, 0);
    const float bb = bias[c * 16 + l16];
    z[0] += bb; z[1] += bb; z[2] += bb; z[3] += bb;
    acc[c] = z;
  }
  __syncthreads();   // all waves done reading WP and X -> both may be overwritten
}

__device__ __forceinline__ void lnreg(f32x4 acc[4], const float gl[4], const float bl[4]) {
#pragma unroll
  for (int j = 0; j < 4; ++j) {
    float sm = acc[0][j] + acc[1][j] + acc[2][j] + acc[3][j];
    sm += __shfl_xor(sm, 1); sm += __shfl_xor(sm, 2);
    sm += __shfl_xor(sm, 4); sm += __shfl_xor(sm, 8);
    const float m = sm * (1.f / 64.f);
    float d[4], vs = 0.f;
#pragma unroll
    for (int c = 0; c < 4; ++c) { d[c] = acc[c][j] - m; vs += d[c] * d[c]; }
    vs += __shfl_xor(vs, 1); vs += __shfl_xor(vs, 2);
    vs += __shfl_xor(vs, 4); vs += __shfl_xor(vs, 8);
    const float rs = rsqrtf(vs * (1.f / 64.f) + 1e-5f);
#pragma unroll
    for (int c = 0; c < 4; ++c) acc[c][j] = d[c] * rs * gl[c] + bl[c];
  }
}

// ---------------- stage-1 per-window focus iteration (bf16 MFMA) ----------------
// QKV is bf16 (rope math still f32, via precomputed rope table rows 0..63).
// LDS aliasing: A0 = Xq then LN'd q; A1 = Xk then LN'd k; A2 = Xv then Vt (transposed v).
__global__ __launch_bounds__(256) void focus_win(
    int it, float sscale, const __bf16* __restrict__ QKV,
    __bf16* __restrict__ qst, __bf16* __restrict__ kst, __bf16* __restrict__ vst,
    __bf16* __restrict__ ast, __bf16* __restrict__ ybuf, float* __restrict__ dpart,
    const float2* __restrict__ rope,
    const __bf16* __restrict__ Wqht, const __bf16* __restrict__ Wkht,
    const __bf16* __restrict__ Wvht,
    const float* __restrict__ bq, const float* __restrict__ bk, const float* __restrict__ bv,
    const float* __restrict__ lng, const float* __restrict__ lnb) {
  __shared__ __align__(16) __bf16 A0[64][72], A1[64][72], A2[64][72];
  __shared__ __align__(16) __bf16 WP[64][72];
  __shared__ float red[256];
  __shared__ float flagsh;
  const int tid = threadIdx.x;
  const int bid = blockIdx.x;
  const int s = bid / 384, rem = bid % 384, w = rem >> 4, bh = rem & 15;
  const int b = bh >> 3, h = bh & 7;

  if (it == 2) {
    if (tid == 0) {
      const int g = s * 24 + w;
      float sum = 0.f;
      for (int i = 0; i < 16; ++i) sum += dpart[g * 16 + i];
      flagsh = (sum * (1.f / 65536.f) < 0.5f) ? 1.f : 0.f;
    }
    __syncthreads();
    if (flagsh > 0.5f) return;
  }

  const size_t sb = (size_t)bid * 4096;
  if (it == 0) {
    const int qrow0 = s * 3072 + b * 1536 + w * 64;
    const int krow0 = s * 3072 + b * 1536 + (w == 0 ? 0 : w * 64 - 8);
    for (int idx = tid; idx < 2048; idx += 256) {
      const int r = idx >> 5, j = idx & 31;
      const float2 rc = rope[r * 32 + j];
      const float sn = rc.x, cs = rc.y;
      const bf16x2 qp = *(const bf16x2*)&QKV[(size_t)(qrow0 + r) * 1536 + h * 64 + 2 * j];
      const float qr = (float)qp[0], qi = (float)qp[1];
      const float q0 = qr * cs - qi * sn;
      const float q1 = qr * sn + qi * cs;
      const bf16x2 qv = {(__bf16)q0, (__bf16)q1};
      *(bf16x2*)&A0[r][2 * j] = qv;
      *(bf16x2*)&qst[sb + r * 64 + 2 * j] = qv;
      const bf16x2 kp2 = *(const bf16x2*)&QKV[(size_t)(krow0 + r) * 1536 + 512 + h * 64 + 2 * j];
      const float kr = (float)kp2[0], ki = (float)kp2[1];
      A1[r][2 * j]     = (__bf16)(kr * cs - ki * sn);
      A1[r][2 * j + 1] = (__bf16)(kr * sn + ki * cs);
      const bf16x2 vp2 = *(const bf16x2*)&QKV[(size_t)(krow0 + r) * 1536 + 1024 + h * 64 + 2 * j];
      A2[r][2 * j] = vp2[0]; A2[r][2 * j + 1] = vp2[1];
    }
  } else {
    for (int idx = tid; idx < 512; idx += 256) {
      const int r = idx >> 3, c8 = (idx & 7) << 3;
      *(bf16x8*)&A0[r][c8] = *(const bf16x8*)&qst[sb + (size_t)r * 64 + c8];
      *(bf16x8*)&A1[r][c8] = *(const bf16x8*)&kst[sb + (size_t)r * 64 + c8];
      *(bf16x8*)&A2[r][c8] = *(const bf16x8*)&vst[sb + (size_t)r * 64 + c8];
    }
  }
  // (barrier inside first proj64 covers the staging writes)

  const int wv = tid >> 6, lane = tid & 63, g4 = lane >> 4, l16 = lane & 15;
  const int row = wv * 16 + g4 * 4;
  float gl[4], bl[4];
#pragma unroll
  for (int c = 0; c < 4; ++c) { gl[c] = lng[c * 16 + l16]; bl[c] = lnb[c * 16 + l16]; }

  f32x4 acc[4];
  // ---- qt = LN(A0 @ Wq + bq) -> back into A0 ----
  proj64(tid, A0, WP, Wqht, bq, acc);
  lnreg(acc, gl, bl);
#pragma unroll
  for (int c = 0; c < 4; ++c)
#pragma unroll
    for (int j = 0; j < 4; ++j) A0[row + j][c * 16 + l16] = (__bf16)acc[c][j];

  // ---- kt = A1 @ Wk + bk (store raw), LN -> back into A1 ----
  proj64(tid, A1, WP, Wkht, bk, acc);
  if (it <= 1)
#pragma unroll
    for (int c = 0; c < 4; ++c)
#pragma unroll
      for (int j = 0; j < 4; ++j) kst[sb + (size_t)(row + j) * 64 + c * 16 + l16] = (__bf16)acc[c][j];
  lnreg(acc, gl, bl);
#pragma unroll
  for (int c = 0; c < 4; ++c)
#pragma unroll
    for (int j = 0; j < 4; ++j) A1[row + j][c * 16 + l16] = (__bf16)acc[c][j];

  // ---- vt = A2 @ Wv + bv (store raw), transposed -> back into A2 ----
  proj64(tid, A2, WP, Wvht, bv, acc);
  if (it <= 1)
#pragma unroll
    for (int c = 0; c < 4; ++c)
#pragma unroll
      for (int j = 0; j < 4; ++j) vst[sb + (size_t)(row + j) * 64 + c * 16 + l16] = (__bf16)acc[c][j];
#pragma unroll
  for (int c = 0; c < 4; ++c) {
    bf16x4 pv = {(__bf16)acc[c][0], (__bf16)acc[c][1], (__bf16)acc[c][2], (__bf16)acc[c][3]};
    *(bf16x4*)&A2[c * 16 + l16][row] = pv;   // Vt[d][key]
  }
  __syncthreads();   // A0/A1/A2 new roles visible to all waves

  const bf16x8 aq0 = *(const bf16x8*)&A0[wv * 16 + l16][8 * g4];
  const bf16x8 aq1 = *(const bf16x8*)&A0[wv * 16 + l16][32 + 8 * g4];
  f32x4 sreg[4];
#pragma unroll
  for (int c = 0; c < 4; ++c) {
    f32x4 z = (f32x4){0.f, 0.f, 0.f, 0.f};
    const bf16x8 b0 = *(const bf16x8*)&A1[c * 16 + l16][8 * g4];
    const bf16x8 b1 = *(const bf16x8*)&A1[c * 16 + l16][32 + 8 * g4];
    z = __builtin_amdgcn_mfma_f32_16x16x32_bf16(aq0, b0, z, 0, 0, 0);
    z = __builtin_amdgcn_mfma_f32_16x16x32_bf16(aq1, b1, z, 0, 0, 0);
    sreg[c] = z * sscale;
  }
#pragma unroll
  for (int j = 0; j < 4; ++j) {
    float mx = fmaxf(fmaxf(sreg[0][j], sreg[1][j]), fmaxf(sreg[2][j], sreg[3][j]));
    mx = fmaxf(mx, __shfl_xor(mx, 1)); mx = fmaxf(mx, __shfl_xor(mx, 2));
    mx = fmaxf(mx, __shfl_xor(mx, 4)); mx = fmaxf(mx, __shfl_xor(mx, 8));
    float ps = 0.f;
#pragma unroll
    for (int c = 0; c < 4; ++c) { const float e = expf(sreg[c][j] - mx); sreg[c][j] = e; ps += e; }
    ps += __shfl_xor(ps, 1); ps += __shfl_xor(ps, 2);
    ps += __shfl_xor(ps, 4); ps += __shfl_xor(ps, 8);
    const float inv = 1.f / ps;
#pragma unroll
    for (int c = 0; c < 4; ++c) sreg[c][j] *= inv;
  }
#pragma unroll
  for (int c = 0; c < 4; ++c)
#pragma unroll
    for (int j = 0; j < 4; ++j) WP[row + j][c * 16 + l16] = (__bf16)sreg[c][j];
  const bf16x8 pa0 = *(const bf16x8*)&WP[wv * 16 + l16][8 * g4];
  const bf16x8 pa1 = *(const bf16x8*)&WP[wv * 16 + l16][32 + 8 * g4];
  f32x4 o[4];
#pragma unroll
  for (int dt = 0; dt < 4; ++dt) {
    f32x4 z = (f32x4){0.f, 0.f, 0.f, 0.f};
    const bf16x8 b0 = *(const bf16x8*)&A2[dt * 16 + l16][8 * g4];
    const bf16x8 b1 = *(const bf16x8*)&A2[dt * 16 + l16][32 + 8 * g4];
    z = __builtin_amdgcn_mfma_f32_16x16x32_bf16(pa0, b0, z, 0, 0, 0);
    z = __builtin_amdgcn_mfma_f32_16x16x32_bf16(pa1, b1, z, 0, 0, 0);
    o[dt] = z;
  }

  if (it == 0) {
#pragma unroll
    for (int dt = 0; dt < 4; ++dt)
#pragma unroll
      for (int j = 0; j < 4; ++j) {
        const size_t gi = sb + (size_t)(row + j) * 64 + dt * 16 + l16;
        const float a = o[dt][j];
        ast[gi] = (__bf16)a;
        qst[gi] = (__bf16)((float)qst[gi] + a);
      }
  } else if (it == 1) {
    float loc = 0.f;
#pragma unroll
    for (int dt = 0; dt < 4; ++dt)
#pragma unroll
      for (int j = 0; j < 4; ++j) {
        const size_t gi = sb + (size_t)(row + j) * 64 + dt * 16 + l16;
        const float a = o[dt][j];
        loc += fabsf(a - (float)ast[gi]);
        qst[gi] = (__bf16)((float)qst[gi] + a);
        ybuf[((size_t)((s * 2 + b) * 1536 + w * 64 + row + j)) * 512 + h * 64 + dt * 16 + l16] = (__bf16)a;
      }
    red[tid] = loc;
    __syncthreads();
    for (int o2 = 128; o2; o2 >>= 1) { if (tid < o2) red[tid] += red[tid + o2]; __syncthreads(); }
    if (tid == 0) dpart[bid] = red[0];
  } else {
#pragma unroll
    for (int dt = 0; dt < 4; ++dt)
#pragma unroll
      for (int j = 0; j < 4; ++j)
        ybuf[((size_t)((s * 2 + b) * 1536 + w * 64 + row + j)) * 512 + h * 64 + dt * 16 + l16] = (__bf16)o[dt][j];
  }
}

// ---------------- final-focus projection+LN, one op per block (q/k/v split) ----------------
// Grid (384, 3): x = chunk-unit (bh fastest -> XCD-local), y = op (0=q,1=k,2=v).
// it0 rope via precomputed table (bit-identical values).
__global__ __launch_bounds__(256) void fprojv(
    int it, float sscale, const float* __restrict__ flagp,
    const __bf16* __restrict__ QKV, const float2* __restrict__ rope,
    __bf16* __restrict__ curq, __bf16* __restrict__ kcur, __bf16* __restrict__ vcur,
    __bf16* __restrict__ qpack, __bf16* __restrict__ kpack, __bf16* __restrict__ vpack,
    const __bf16* __restrict__ Wqht, const __bf16* __restrict__ Wkht,
    const __bf16* __restrict__ Wvht,
    const float* __restrict__ bq, const float* __restrict__ bk, const float* __restrict__ bv,
    const float* __restrict__ lng, const float* __restrict__ lnb) {
  if (it == 2 && flagp[0] > 0.5f) return;
  __shared__ __align__(16) __bf16 X[64][72];
  __shared__ __align__(16) __bf16 Y[64][72];
  __shared__ __align__(16) __bf16 WP[64][72];
  const int tid = threadIdx.x;
  const int u = blockIdx.x, op = blockIdx.y;
  const int bh = u & 15, chunk = u >> 4;
  const size_t base = (size_t)bh * 98304 + (size_t)chunk * 4096;   // [t][64] element region

  if (it == 0) {
    const int t0 = chunk * 64;
    const int bb2 = bh >> 3, hh = bh & 7;
    if (op == 2) {
      // v: never roped -- pure bf16 vector copy from QKV cols [1024,1536)
      for (int idx = tid; idx < 512; idx += 256) {
        const int r = idx >> 3, c8 = (idx & 7) << 3;
        *(bf16x8*)&X[r][c8] =
            *(const bf16x8*)&QKV[(size_t)(bb2 * 1536 + t0 + r) * 1536 + 1024 + hh * 64 + c8];
      }
    } else {
      const int off = (op == 0) ? 0 : 512;
      for (int idx = tid; idx < 2048; idx += 256) {
        const int r = idx >> 5, j = idx & 31;
        const int t = t0 + r;
        const __bf16* src = QKV + (size_t)(bb2 * 1536 + t) * 1536 + off;
        const float2 rc = rope[t * 32 + j];
        const float sn = rc.x, cs = rc.y;
        const bf16x2 p2 = *(const bf16x2*)&src[hh * 64 + 2 * j];
        const float xr = (float)p2[0], xi = (float)p2[1];
        const float v0 = xr * cs - xi * sn;
        const float v1 = xr * sn + xi * cs;
        const bf16x2 pv = {(__bf16)v0, (__bf16)v1};
        *(bf16x2*)&X[r][2 * j] = pv;
        if (op == 0) *(bf16x2*)&curq[base + (size_t)r * 64 + 2 * j] = pv;
      }
    }
  } else {
    const __bf16* ch = (op == 0) ? curq : (op == 1) ? kcur : vcur;
    for (int idx = tid; idx < 512; idx += 256) {
      const int r = idx >> 3, c8 = (idx & 7) << 3;
      *(bf16x8*)&X[r][c8] = *(const bf16x8*)&ch[base + (size_t)r * 64 + c8];
    }
  }
  // (proj64's internal barrier covers the staging writes)

  const int wv = tid >> 6, lane = tid & 63, g4 = lane >> 4, l16 = lane & 15;
  const int row = wv * 16 + g4 * 4;

  const __bf16* Wg = (op == 0) ? Wqht : (op == 1) ? Wkht : Wvht;
  const float* bias = (op == 0) ? bq : (op == 1) ? bk : bv;
  f32x4 acc[4];
  proj64(tid, X, WP, Wg, bias, acc);

  if (op == 0) {
    float gl[4], bl[4];
#pragma unroll
    for (int c = 0; c < 4; ++c) { gl[c] = lng[c * 16 + l16]; bl[c] = lnb[c * 16 + l16]; }
    lnreg(acc, gl, bl);
#pragma unroll
    for (int c = 0; c < 4; ++c)
#pragma unroll
      for (int j = 0; j < 4; ++j) Y[row + j][c * 16 + l16] = (__bf16)(acc[c][j] * sscale);
    __syncthreads();
#pragma unroll
    for (int ii = 0; ii < 2; ++ii) {
      const int sg = tid * 2 + ii;               // 0..511
      const int g = sg >> 7, s = sg & 127;
      const int t = s >> 6, g4p = (s >> 4) & 3, l16p = s & 15;
      bf16x8 pv = *(const bf16x8*)&Y[g * 16 + l16p][t * 32 + 8 * g4p];
      *(bf16x8*)&qpack[base + (size_t)g * 1024 + (size_t)s * 8] = pv;
    }
  } else if (op == 1) {
#pragma unroll
    for (int c = 0; c < 4; ++c)
#pragma unroll
      for (int j = 0; j < 4; ++j)
        kcur[base + (size_t)(row + j) * 64 + c * 16 + l16] = (__bf16)acc[c][j];
    float gl[4], bl[4];
#pragma unroll
    for (int c = 0; c < 4; ++c) { gl[c] = lng[c * 16 + l16]; bl[c] = lnb[c * 16 + l16]; }
    lnreg(acc, gl, bl);
#pragma unroll
    for (int c = 0; c < 4; ++c)
#pragma unroll
      for (int j = 0; j < 4; ++j) Y[row + j][c * 16 + l16] = (__bf16)acc[c][j];
    __syncthreads();
#pragma unroll
    for (int ii = 0; ii < 2; ++ii) {
      const int sg = tid * 2 + ii;
      const int g = sg >> 7, s = sg & 127;
      const int t = s >> 6, g4p = (s >> 4) & 3, l16p = s & 15;
      bf16x8 pv = *(const bf16x8*)&Y[g * 16 + l16p][t * 32 + 8 * g4p];
      *(bf16x8*)&kpack[base + (size_t)g * 1024 + (size_t)s * 8] = pv;
    }
  } else {
#pragma unroll
    for (int c = 0; c < 4; ++c)
#pragma unroll
      for (int j = 0; j < 4; ++j) {
        vcur[base + (size_t)(row + j) * 64 + c * 16 + l16] = (__bf16)acc[c][j];
        Y[row + j][c * 16 + l16] = (__bf16)acc[c][j];
      }
    __syncthreads();
#pragma unroll
    for (int ii = 0; ii < 2; ++ii) {
      const int sg = tid * 2 + ii;               // 0..511 = dt*128 + s
      const int dt = sg >> 7, s = sg & 127;
      const int t = s >> 6, g4p = (s >> 4) & 3, l16p = s & 15;
      bf16x8 pv;
#pragma unroll
      for (int j = 0; j < 8; ++j)
        pv[j] = Y[t * 32 + 8 * g4p + j][dt * 16 + l16p];
      *(bf16x8*)&vpack[base + (size_t)sg * 8] = pv;
    }
  }
}

// ---------------- final-focus flash attention: 16 q-rows/block (1 strip), 4-way k-split,
// no-max softmax. Grid 1536: bid = qc*16 + bh (96 q-chunks, bh fastest for XCD-local L2).
// (256,3): natural VGPR, no spill. Pipelined k-loop (R26). R28's fdec-fold REVERTED:
// grafting the cold it1 reduction tail dropped VGPR 84->76 and broke the hot-loop
// pipeline (2x dur). fdec stays a separate kernel.
__global__ __launch_bounds__(256, 3) void fattn(
    int it,
    const __bf16* __restrict__ qpack, const __bf16* __restrict__ kpack,
    const __bf16* __restrict__ vpack,
    __bf16* __restrict__ Rout, __bf16* __restrict__ aprev, __bf16* __restrict__ curq,
    float* __restrict__ dpart, const float* __restrict__ flagp) {
  if (it == 2 && flagp[0] > 0.5f) return;
  __shared__ __align__(16) __bf16 Pl[4][16][72]; // per-wave P transpose strip
  __shared__ float Ob[4][16][65];                // per-wave O-numerator partials
  __shared__ float Ll[4][16];                    // per-wave l partials
  __shared__ float redm[4];
  const int tid = threadIdx.x;
  const int wv = tid >> 6, lane = tid & 63;
  const int g4 = lane >> 4, l16 = lane & 15;
  const int bid = blockIdx.x;
  const int bh = bid & 15, qc = bid >> 4;          // qc in 0..95
  const int bb2 = bh >> 3, hh = bh & 7;            // batch, head for reorder write
  const size_t base = (size_t)bh * (1536 * 64);
  const __bf16* qp = qpack + base;
  const __bf16* kp = kpack + base;
  const __bf16* vp = vpack + base;
  const int q0 = qc * 16;

  bf16x8 aq[2];
#pragma unroll
  for (int t = 0; t < 2; ++t)
    aq[t] = *(const bf16x8*)&qp[(size_t)qc * 1024 + (size_t)(t * 64 + lane) * 8];

  f32x4 oacc[4];
#pragma unroll
  for (int dt = 0; dt < 4; ++dt) oacc[dt] = (f32x4){0.f, 0.f, 0.f, 0.f};
  float lsum[4] = {0.f, 0.f, 0.f, 0.f};

  const int kbeg = wv * 384, kend = kbeg + 384;
  // prologue: first tile's K fragments
  bf16x8 bk[4][2];
#pragma unroll
  for (int c = 0; c < 4; ++c)
#pragma unroll
    for (int t = 0; t < 2; ++t)
      bk[c][t] = *(const bf16x8*)&kp[(size_t)((kbeg >> 4) + c) * 1024 + (size_t)(t * 64 + lane) * 8];

  for (int k0 = kbeg; k0 < kend; k0 += 64) {
    // prefetch next tile's K fragments (latency hidden under this tile's compute)
    const int k1 = k0 + 64;
    bf16x8 bkn[4][2];
    if (k1 < kend) {
#pragma unroll
      for (int c = 0; c < 4; ++c)
#pragma unroll
        for (int t = 0; t < 2; ++t)
          bkn[c][t] = *(const bf16x8*)&kp[(size_t)((k1 >> 4) + c) * 1024 + (size_t)(t * 64 + lane) * 8];
    }

    // QK^T MFMAs
    f32x4 s[4];
#pragma unroll
    for (int c = 0; c < 4; ++c) {
      f32x4 a = (f32x4){0.f, 0.f, 0.f, 0.f};
      a = __builtin_amdgcn_mfma_f32_16x16x32_bf16(aq[0], bk[c][0], a, 0, 0, 0);
      a = __builtin_amdgcn_mfma_f32_16x16x32_bf16(aq[1], bk[c][1], a, 0, 0, 0);
      s[c] = a;   // Q pre-scaled by sscale
    }

    // V fragments: batch-issued so their latency hides under exp + LDS roundtrip
    bf16x8 vv[4][2];
#pragma unroll
    for (int dt = 0; dt < 4; ++dt) {
      const size_t vb = (size_t)((k0 >> 6) * 4 + dt) * 1024;
      vv[dt][0] = *(const bf16x8*)&vp[vb + (size_t)lane * 8];
      vv[dt][1] = *(const bf16x8*)&vp[vb + (size_t)(64 + lane) * 8];
    }

    // no-max softmax: p = exp(s); per-lane partial l (cross-lane reduce deferred)
#pragma unroll
    for (int c = 0; c < 4; ++c)
#pragma unroll
      for (int j = 0; j < 4; ++j) {
        const float p = __expf(s[c][j]);
        s[c][j] = p;
        lsum[j] += p;
      }
    // P C-layout -> A-layout via per-wave LDS strip
#pragma unroll
    for (int c = 0; c < 4; ++c)
#pragma unroll
      for (int j = 0; j < 4; ++j)
        Pl[wv][g4 * 4 + j][c * 16 + l16] = (__bf16)s[c][j];
    bf16x8 pa[2];
#pragma unroll
    for (int t = 0; t < 2; ++t)
      pa[t] = *(const bf16x8*)&Pl[wv][l16][t * 32 + 8 * g4];

    // PV MFMAs consume the prefetched V fragments
#pragma unroll
    for (int dt = 0; dt < 4; ++dt) {
      oacc[dt] = __builtin_amdgcn_mfma_f32_16x16x32_bf16(pa[0], vv[dt][0], oacc[dt], 0, 0, 0);
      oacc[dt] = __builtin_amdgcn_mfma_f32_16x16x32_bf16(pa[1], vv[dt][1], oacc[dt], 0, 0, 0);
    }

    if (k1 < kend) {
#pragma unroll
      for (int c = 0; c < 4; ++c) {
        bk[c][0] = bkn[c][0];
        bk[c][1] = bkn[c][1];
      }
    }
  }

  // one deferred cross-lane l reduction
#pragma unroll
  for (int j = 0; j < 4; ++j) {
    lsum[j] += __shfl_xor(lsum[j], 1);
    lsum[j] += __shfl_xor(lsum[j], 2);
    lsum[j] += __shfl_xor(lsum[j], 4);
    lsum[j] += __shfl_xor(lsum[j], 8);
  }
  if (l16 == 0) {
#pragma unroll
    for (int j = 0; j < 4; ++j) Ll[wv][g4 * 4 + j] = lsum[j];
  }
#pragma unroll
  for (int dt = 0; dt < 4; ++dt)
#pragma unroll
    for (int j = 0; j < 4; ++j)
      Ob[wv][g4 * 4 + j][dt * 16 + l16] = oacc[dt][j];
  __syncthreads();

  // merge (pure sums): each wave merges 4 rows, lane = column
  float loc = 0.f;
  const int col = lane;
#pragma unroll
  for (int rr = 0; rr < 4; ++rr) {
    const int r = wv * 4 + rr;
    const float L = Ll[0][r] + Ll[1][r] + Ll[2][r] + Ll[3][r];
    const float o = (Ob[0][r][col] + Ob[1][r][col] +
                     Ob[2][r][col] + Ob[3][r][col]) / L;
    const size_t gi = base + (size_t)(q0 + r) * 64 + col;
    if (it == 1) loc += fabsf(o - (float)aprev[gi]);
    if (it > 0)   // final output path: reordered bf16 GEMM input (a0 never final)
      Rout[(size_t)(bb2 * 1536 + q0 + r) * 512 + hh * 64 + col] = (__bf16)o;
    if (it == 0) { aprev[gi] = (__bf16)o; curq[gi] = (__bf16)((float)curq[gi] + o); }
    else if (it == 1) curq[gi] = (__bf16)((float)curq[gi] + o);  // aprev never read after it1
  }
  if (it == 1) {
    for (int o2 = 32; o2; o2 >>= 1) loc += __shfl_xor(loc, o2, 64);
    if (lane == 0) redm[wv] = loc;
    __syncthreads();
    if (tid == 0) dpart[bid] = redm[0] + redm[1] + redm[2] + redm[3];
  }
}

__global__ void fdec(const float* __restrict__ dpart, float* __restrict__ flagp) {
  const int l = threadIdx.x;   // 64 threads; 1536 partials
  float s = 0.f;
  for (int i = 0; i < 24; ++i) s += dpart[l * 24 + i];
  for (int o = 32; o; o >>= 1) s += __shfl_xor(s, o, 64);
  if (l == 0) flagp[0] = (s * (1.f / 1572864.f) < 0.5f) ? 1.f : 0.f;
}

// ---------------- launch ----------------
extern "C" void kernel_launch(void* const* d_in, const int* in_sizes, int n_in,
                              void* d_out, int out_size, void* d_ws, size_t ws_size,
                              hipStream_t stream) {
  const float* x     = (const float*)d_in[0];
  const float* xa    = (const float*)d_in[1];
  const float* Wq    = (const float*)d_in[2];
  const float* Wkv   = (const float*)d_in[3];
  const float* Wo    = (const float*)d_in[4];
  const float* lna_g = (const float*)d_in[5];
  const float* lna_b = (const float*)d_in[6];
  const float* lnb_g = (const float*)d_in[7];
  const float* lnb_b = (const float*)d_in[8];
  const float* Wq_hd = (const float*)d_in[9];
  const float* bq_hd = (const float*)d_in[10];
  const float* Wk_hd = (const float*)d_in[11];
  const float* bk_hd = (const float*)d_in[12];
  const float* Wv_hd = (const float*)d_in[13];
  const float* bv_hd = (const float*)d_in[14];
  const float* theta = (const float*)d_in[15];
  float* out = (float*)d_out;
  float* ws = (float*)d_ws;
  if (ws_size < (size_t)WS_FLOATS * sizeof(float)) return;

  float* freq = ws + OFF_FREQ;
  float2* rope = (float2*)(ws + OFF_RT);
  __bf16* lnAb = (__bf16*)(ws + OFF_LNA);
  __bf16* Wallt = (__bf16*)(ws + OFF_WALL);
  __bf16* Wot  = (__bf16*)(ws + OFF_WOT);
  __bf16* Wqht = (__bf16*)(ws + OFF_WQH);
  __bf16* Wkht = (__bf16*)(ws + OFF_WKH);
  __bf16* Wvht = (__bf16*)(ws + OFF_WVH);
  __bf16* QKV = (__bf16*)(ws + OFF_QKV);
  __bf16* ybuf = (__bf16*)(ws + OFF_YBUF);
  __bf16* qst = (__bf16*)(ws + OFF_QST);
  __bf16* kst = (__bf16*)(ws + OFF_KST);
  __bf16* vst = (__bf16*)(ws + OFF_VST);
  __bf16* ast = (__bf16*)(ws + OFF_AST);
  __bf16* curq = (__bf16*)(ws + OFF_CURQ);
  __bf16* kcur = (__bf16*)(ws + OFF_KCUR);
  __bf16* vcur = (__bf16*)(ws + OFF_VCUR);
  __bf16* apr  = (__bf16*)(ws + OFF_APR);
  float* dp1  = ws + OFF_DP1;
  float* dpf2 = ws + OFF_DPF2;   // 1536 fattn diff partials
  float* flg  = ws + OFF_FLAG;
  __bf16* qpack = (__bf16*)(ws + OFF_QPK);
  __bf16* kpack = (__bf16*)(ws + OFF_KPK);
  __bf16* vpack = (__bf16*)(ws + OFF_VPK);

  const float sc[3] = {0.125f,
                       (float)(0.125 * sqrt(1.0 / 0.995)),
                       (float)(0.125 * sqrt(1.0 / 0.99))};

  conv_all<<<452, 256, 0, stream>>>(theta, Wq, Wkv, Wo, Wq_hd, Wk_hd, Wv_hd,
                                    freq, rope, Wallt, Wot, Wqht, Wkht, Wvht);

  // ---- stage 1: both slides ----
  ln512w<<<1536, 256, 0, stream>>>(x, xa, lna_g, lna_b, lnAb);
  gemm_bfb<<<dim3(24, 48), 256, 0, stream>>>(lnAb, Wallt, QKV, 1536, 512);
  for (int it = 0; it < 3; ++it)
    focus_win<<<768, 256, 0, stream>>>(it, sc[it], QKV, qst, kst, vst, ast, ybuf, dp1,
                                       rope, Wqht, Wkht, Wvht, bq_hd, bk_hd, bv_hd,
                                       lnb_g, lnb_b);

  // ---- final focus ----
  ln512bw<<<1536, 256, 0, stream>>>(ybuf, lna_g, lna_b, lnAb);
  gemm_ff<<<dim3(24, 24), 256, 0, stream>>>(lnAb, Wallt, QKV);

  for (int it = 0; it < 3; ++it) {
    fprojv<<<dim3(384, 3), 256, 0, stream>>>(it, sc[it], flg, QKV, rope, curq, kcur, vcur,
                                             qpack, kpack, vpack,
                                             Wqht, Wkht, Wvht, bq_hd, bk_hd, bv_hd,
                                             lnb_g, lnb_b);
    fattn<<<1536, 256, 0, stream>>>(it, qpack, kpack, vpack,
                                    lnAb, apr, curq, dpf2, flg);
    if (it == 1) fdec<<<1, 64, 0, stream>>>(dpf2, flg);
  }

  // ---- output projection (fattn wrote reordered bf16 R directly into lnAb) ----
  gemm_bf<<<dim3(8, 24), 256, 0, stream>>>(lnAb, Wot, out, 512, 512);
}

// Round 30
// 200.087 us; speedup vs baseline: 1.2091x; 1.0340x over previous
//
#include <hip/hip_runtime.h>
#include <math.h>

// ---------------- workspace layout (floats) ----------------
#define S1SZ (768*4096)
#define FSZ  (16*1536*64)

#define OFF_FREQ 0
#define OFF_LNA  64
// bf16 buffers packed into the old lnA region (float-counted offsets)
#define OFF_WALL (OFF_LNA + 1572864)     // Wallt bf16 [1536][512]
#define OFF_WOT  (OFF_WALL + 393216)     // Wot  bf16 [512][512]
#define OFF_WQH  (OFF_WOT + 131072)      // Wqht bf16 [64][64]
#define OFF_WKH  (OFF_WQH + 2048)
#define OFF_WVH  (OFF_WKH + 2048)
#define OFF_QKV  (OFF_LNA + 6144*512)    // bf16 QKV [6144][1536] (half slot used)
#define OFF_YBUF (OFF_QKV + 6144*1536)   // bf16 ybuf [6144][512] (half slot used)
#define OFF_STATE (OFF_YBUF + 6144*512)
// stage-1 state bf16 (half of each slot used; offsets unchanged)
#define OFF_QST OFF_STATE
#define OFF_KST (OFF_QST + S1SZ)
#define OFF_VST (OFF_KST + S1SZ)
#define OFF_AST (OFF_VST + S1SZ)
// rope table float2[1536][32] -- upper (unused) half of the AST slot: stage-1 ast (bf16)
// occupies only [OFF_AST, OFF_AST + S1SZ/2); final-focus buffers end at OFF_STATE+8652288.
#define OFF_RT   (OFF_AST + S1SZ/2)
// final-focus buffers overlay the stage-1 state region (stage-1 state dead by then)
// curq/kcur/vcur/apr all bf16 (half slot used).
#define OFF_CURQ OFF_STATE
#define OFF_KCUR (OFF_CURQ + FSZ)
#define OFF_VCUR (OFF_KCUR + FSZ)
#define OFF_APR  (OFF_VCUR + FSZ)
#define OFF_QPK  (OFF_APR + FSZ)         // bf16 qpack (FSZ/2 floats)
#define OFF_KPK  (OFF_QPK + FSZ/2)
#define OFF_VPK  (OFF_KPK + FSZ/2)
#define OFF_DPF2 (OFF_VPK + FSZ/2)       // 1536 fattn diff partials
#define OFF_DP1  (OFF_STATE + 4*S1SZ)
#define OFF_DPF  (OFF_DP1 + 768)
#define OFF_FLAG (OFF_DPF + 512)
#define WS_FLOATS (OFF_FLAG + 64)

typedef __bf16 bf16x8 __attribute__((ext_vector_type(8)));
typedef __bf16 bf16x4 __attribute__((ext_vector_type(4)));
typedef __bf16 bf16x2 __attribute__((ext_vector_type(2)));
typedef float f32x4 __attribute__((ext_vector_type(4)));

// fragment-major packing: per 16-row group of a [rows][64] bf16 matrix,
// element (t,g4,l16,j) at group*1024 + (t*64 + g4*16 + l16)*8 + j.
// A wave's MFMA fragment load (16B/lane) is then lane-contiguous (1KB).

// ---------------- all weight conversions + freq + rope table in one launch ----------------
// id < 256: weight tiles; 256-258: head weights; 259: freq; 260-451: rope table
// rope[t*32+j] = {sin, cos}(t * freq_j), arithmetic bit-identical to the old per-kernel
// sincosf path (f64 fbv -> f32 freq -> f32 mult -> sincosf).
__global__ __launch_bounds__(256) void conv_all(
    const float* __restrict__ theta_p,
    const float* __restrict__ Wq, const float* __restrict__ Wkv, const float* __restrict__ Wo,
    const float* __restrict__ Wqh, const float* __restrict__ Wkh, const float* __restrict__ Wvh,
    float* __restrict__ freq, float2* __restrict__ rope,
    __bf16* __restrict__ Wallt, __bf16* __restrict__ Wot,
    __bf16* __restrict__ Wqht, __bf16* __restrict__ Wkht, __bf16* __restrict__ Wvht) {
  int id = blockIdx.x;
  if (id >= 260) {  // rope table: 192 blocks x 256 entries
    const int gidx = (id - 260) * 256 + threadIdx.x;   // 0..49151
    const int t = gidx >> 5, j = gidx & 31;
    double stop = 2595.0 * log10(21.0);
    double ls = (j == 31) ? stop : (double)j * (stop / 31.0);
    double fbv = 200.0 * (pow(10.0, ls / 2595.0) - 1.0) / 1000.0;
    const float fj = (theta_p[0] / 220.0f) * (float)fbv;
    float sn, cs;
    sincosf((float)t * fj, &sn, &cs);
    rope[gidx] = make_float2(sn, cs);
    return;
  }
  if (id == 259) {  // freq table (f64 to match np's f64-derived fb)
    int i = threadIdx.x;
    if (i < 32) {
      double stop = 2595.0 * log10(21.0);
      double ls = (i == 31) ? stop : (double)i * (stop / 31.0);
      double fbv = 200.0 * (pow(10.0, ls / 2595.0) - 1.0) / 1000.0;
      freq[i] = (theta_p[0] / 220.0f) * (float)fbv;
    }
    return;
  }
  const float* src; __bf16* dst; int N, nt, kt;
  if (id < 64)       { src = Wq;  dst = Wallt;                     N = 512;  nt = id & 7;  kt = id >> 3; }
  else if (id < 192) { id -= 64;  src = Wkv; dst = Wallt + (size_t)512 * 512; N = 1024; nt = id & 15; kt = id >> 4; }
  else if (id < 256) { id -= 192; src = Wo;  dst = Wot;            N = 512;  nt = id & 7;  kt = id >> 3; }
  else { int t = id - 256; src = (t == 0) ? Wqh : (t == 1) ? Wkh : Wvh;
         dst = (t == 0) ? Wqht : (t == 1) ? Wkht : Wvht; N = 64; nt = 0; kt = 0; }
  const int Kd = (N == 64) ? 64 : 512;
  __shared__ float T[64][65];
  const int tid = threadIdx.x;
  const int n0 = nt * 64, k0 = kt * 64;
  for (int idx = tid; idx < 4096; idx += 256) {
    const int r = idx >> 6, c = idx & 63;
    T[r][c] = src[(size_t)(k0 + r) * N + n0 + c];
  }
  __syncthreads();
  for (int idx = tid; idx < 2048; idx += 256) {
    const int n = idx >> 5, kp = (idx & 31) << 1;
    bf16x2 pv = {(__bf16)T[kp][n], (__bf16)T[kp + 1][n]};
    *(bf16x2*)&dst[(size_t)(n0 + n) * Kd + k0 + kp] = pv;
  }
}

// ---------------- LN over 512, wave-per-row (shuffle-only, no barriers) ----------------
// f32 in -> bf16 out. Grid 1536, 4 rows/block (one per wave). rows<3072: src0, else src1.
__global__ __launch_bounds__(256) void ln512w(const float* __restrict__ src0,
                                              const float* __restrict__ src1,
                                              const float* __restrict__ g,
                                              const float* __restrict__ bb,
                                              __bf16* __restrict__ out) {
  const int tid = threadIdx.x, wv = tid >> 6, lane = tid & 63;
  const int r = blockIdx.x * 4 + wv;
  const float* src = (r < 3072) ? (src0 + (size_t)r * 512) : (src1 + (size_t)(r - 3072) * 512);
  const float4 a0 = *(const float4*)&src[lane * 8];
  const float4 a1 = *(const float4*)&src[lane * 8 + 4];
  float v[8] = {a0.x, a0.y, a0.z, a0.w, a1.x, a1.y, a1.z, a1.w};
  float sm = v[0] + v[1] + v[2] + v[3] + v[4] + v[5] + v[6] + v[7];
  sm += __shfl_xor(sm, 1);  sm += __shfl_xor(sm, 2);  sm += __shfl_xor(sm, 4);
  sm += __shfl_xor(sm, 8);  sm += __shfl_xor(sm, 16); sm += __shfl_xor(sm, 32);
  const float mean = sm * (1.f / 512.f);
  float d[8], vs = 0.f;
#pragma unroll
  for (int i = 0; i < 8; ++i) { d[i] = v[i] - mean; vs += d[i] * d[i]; }
  vs += __shfl_xor(vs, 1);  vs += __shfl_xor(vs, 2);  vs += __shfl_xor(vs, 4);
  vs += __shfl_xor(vs, 8);  vs += __shfl_xor(vs, 16); vs += __shfl_xor(vs, 32);
  const float rs = rsqrtf(vs * (1.f / 512.f) + 1e-5f);
  const float4 g0 = *(const float4*)&g[lane * 8];
  const float4 g1 = *(const float4*)&g[lane * 8 + 4];
  const float4 b0 = *(const float4*)&bb[lane * 8];
  const float4 b1 = *(const float4*)&bb[lane * 8 + 4];
  const float gg[8] = {g0.x, g0.y, g0.z, g0.w, g1.x, g1.y, g1.z, g1.w};
  const float bbv[8] = {b0.x, b0.y, b0.z, b0.w, b1.x, b1.y, b1.z, b1.w};
  bf16x8 pv;
#pragma unroll
  for (int i = 0; i < 8; ++i) pv[i] = (__bf16)(d[i] * rs * gg[i] + bbv[i]);
  *(bf16x8*)&out[(size_t)r * 512 + lane * 8] = pv;
}

// ---------------- LN over 512, wave-per-row, bf16 in -> bf16 out ([6144][512]) -------------
__global__ __launch_bounds__(256) void ln512bw(const __bf16* __restrict__ src,
                                               const float* __restrict__ g,
                                               const float* __restrict__ bb,
                                               __bf16* __restrict__ out) {
  const int tid = threadIdx.x, wv = tid >> 6, lane = tid & 63;
  const int r = blockIdx.x * 4 + wv;
  const bf16x8 sv = *(const bf16x8*)&src[(size_t)r * 512 + lane * 8];
  float v[8];
#pragma unroll
  for (int i = 0; i < 8; ++i) v[i] = (float)sv[i];
  float sm = v[0] + v[1] + v[2] + v[3] + v[4] + v[5] + v[6] + v[7];
  sm += __shfl_xor(sm, 1);  sm += __shfl_xor(sm, 2);  sm += __shfl_xor(sm, 4);
  sm += __shfl_xor(sm, 8);  sm += __shfl_xor(sm, 16); sm += __shfl_xor(sm, 32);
  const float mean = sm * (1.f / 512.f);
  float d[8], vs = 0.f;
#pragma unroll
  for (int i = 0; i < 8; ++i) { d[i] = v[i] - mean; vs += d[i] * d[i]; }
  vs += __shfl_xor(vs, 1);  vs += __shfl_xor(vs, 2);  vs += __shfl_xor(vs, 4);
  vs += __shfl_xor(vs, 8);  vs += __shfl_xor(vs, 16); vs += __shfl_xor(vs, 32);
  const float rs = rsqrtf(vs * (1.f / 512.f) + 1e-5f);
  const float4 g0 = *(const float4*)&g[lane * 8];
  const float4 g1 = *(const float4*)&g[lane * 8 + 4];
  const float4 b0 = *(const float4*)&bb[lane * 8];
  const float4 b1 = *(const float4*)&bb[lane * 8 + 4];
  const float gg[8] = {g0.x, g0.y, g0.z, g0.w, g1.x, g1.y, g1.z, g1.w};
  const float bbv[8] = {b0.x, b0.y, b0.z, b0.w, b1.x, b1.y, b1.z, b1.w};
  bf16x8 pv;
#pragma unroll
  for (int i = 0; i < 8; ++i) pv[i] = (__bf16)(d[i] * rs * gg[i] + bbv[i]);
  *(bf16x8*)&out[(size_t)r * 512 + lane * 8] = pv;
}

// ---------------- bf16 MFMA GEMM: C f32 (used for final out projection) ----------------
__global__ __launch_bounds__(256) void gemm_bf(const __bf16* __restrict__ A,
                                               const __bf16* __restrict__ Bt,
                                               float* __restrict__ C, int ldc, int K) {
  __shared__ __align__(16) __bf16 As[128][72];
  __shared__ __align__(16) __bf16 Bs[64][72];
  const int tid = threadIdx.x;
  const int wv = tid >> 6, lane = tid & 63, g4 = lane >> 4, l16 = lane & 15;
  const int m0 = blockIdx.y * 128, n0 = blockIdx.x * 64;
  f32x4 acc[2][4];
#pragma unroll
  for (int m = 0; m < 2; ++m)
#pragma unroll
    for (int n = 0; n < 4; ++n) acc[m][n] = (f32x4){0.f, 0.f, 0.f, 0.f};
  for (int k0 = 0; k0 < K; k0 += 64) {
    __syncthreads();
    for (int idx = tid; idx < 1024; idx += 256) {
      const int r = idx >> 3, c8 = (idx & 7) << 3;
      *(uint4*)&As[r][c8] = *(const uint4*)&A[(size_t)(m0 + r) * K + k0 + c8];
    }
    for (int idx = tid; idx < 512; idx += 256) {
      const int r = idx >> 3, c8 = (idx & 7) << 3;
      *(uint4*)&Bs[r][c8] = *(const uint4*)&Bt[(size_t)(n0 + r) * K + k0 + c8];
    }
    __syncthreads();
#pragma unroll
    for (int t = 0; t < 2; ++t) {
      const bf16x8 a0 = *(const bf16x8*)&As[wv * 32 + l16][t * 32 + 8 * g4];
      const bf16x8 a1 = *(const bf16x8*)&As[wv * 32 + 16 + l16][t * 32 + 8 * g4];
#pragma unroll
      for (int n = 0; n < 4; ++n) {
        const bf16x8 b = *(const bf16x8*)&Bs[n * 16 + l16][t * 32 + 8 * g4];
        acc[0][n] = __builtin_amdgcn_mfma_f32_16x16x32_bf16(a0, b, acc[0][n], 0, 0, 0);
        acc[1][n] = __builtin_amdgcn_mfma_f32_16x16x32_bf16(a1, b, acc[1][n], 0, 0, 0);
      }
    }
  }
#pragma unroll
  for (int m = 0; m < 2; ++m)
#pragma unroll
    for (int n = 0; n < 4; ++n)
#pragma unroll
      for (int j = 0; j < 4; ++j)
        C[(size_t)(m0 + wv * 32 + m * 16 + g4 * 4 + j) * ldc + n0 + n * 16 + l16] = acc[m][n][j];
}

// ---------------- bf16 MFMA GEMM: C bf16 (stage-1 QKV path) --------------
__global__ __launch_bounds__(256) void gemm_bfb(const __bf16* __restrict__ A,
                                                const __bf16* __restrict__ Bt,
                                                __bf16* __restrict__ C, int ldc, int K) {
  __shared__ __align__(16) __bf16 As[128][72];
  __shared__ __align__(16) __bf16 Bs[64][72];
  const int tid = threadIdx.x;
  const int wv = tid >> 6, lane = tid & 63, g4 = lane >> 4, l16 = lane & 15;
  const int m0 = blockIdx.y * 128, n0 = blockIdx.x * 64;
  f32x4 acc[2][4];
#pragma unroll
  for (int m = 0; m < 2; ++m)
#pragma unroll
    for (int n = 0; n < 4; ++n) acc[m][n] = (f32x4){0.f, 0.f, 0.f, 0.f};
  for (int k0 = 0; k0 < K; k0 += 64) {
    __syncthreads();
    for (int idx = tid; idx < 1024; idx += 256) {
      const int r = idx >> 3, c8 = (idx & 7) << 3;
      *(uint4*)&As[r][c8] = *(const uint4*)&A[(size_t)(m0 + r) * K + k0 + c8];
    }
    for (int idx = tid; idx < 512; idx += 256) {
      const int r = idx >> 3, c8 = (idx & 7) << 3;
      *(uint4*)&Bs[r][c8] = *(const uint4*)&Bt[(size_t)(n0 + r) * K + k0 + c8];
    }
    __syncthreads();
#pragma unroll
    for (int t = 0; t < 2; ++t) {
      const bf16x8 a0 = *(const bf16x8*)&As[wv * 32 + l16][t * 32 + 8 * g4];
      const bf16x8 a1 = *(const bf16x8*)&As[wv * 32 + 16 + l16][t * 32 + 8 * g4];
#pragma unroll
      for (int n = 0; n < 4; ++n) {
        const bf16x8 b = *(const bf16x8*)&Bs[n * 16 + l16][t * 32 + 8 * g4];
        acc[0][n] = __builtin_amdgcn_mfma_f32_16x16x32_bf16(a0, b, acc[0][n], 0, 0, 0);
        acc[1][n] = __builtin_amdgcn_mfma_f32_16x16x32_bf16(a1, b, acc[1][n], 0, 0, 0);
      }
    }
  }
#pragma unroll
  for (int m = 0; m < 2; ++m)
#pragma unroll
    for (int n = 0; n < 4; ++n)
#pragma unroll
      for (int j = 0; j < 4; ++j)
        C[(size_t)(m0 + wv * 32 + m * 16 + g4 * 4 + j) * ldc + n0 + n * 16 + l16] =
            (__bf16)acc[m][n][j];
}

// ---------------- fused final-focus QKV GEMMs (one dispatch, branch on blockIdx.x) ---------
// x<8:  q  = LN(y)  @ Wq^T  -> QKV cols [0,512)     (A rows 0..3071)
// x>=8: kv = LN(ya) @ Wkv^T -> QKV cols [512,1536)  (A rows 3072..6143)
__global__ __launch_bounds__(256) void gemm_ff(const __bf16* __restrict__ lnAb,
                                               const __bf16* __restrict__ Wallt,
                                               __bf16* __restrict__ QKV) {
  const int K = 512, ldc = 1536;
  const int nx = blockIdx.x;
  const __bf16* A; const __bf16* Bt; __bf16* C; int n0;
  if (nx < 8) { A = lnAb;                        Bt = Wallt;                        C = QKV;       n0 = nx * 64; }
  else        { A = lnAb + (size_t)3072 * 512;   Bt = Wallt + (size_t)512 * 512;    C = QKV + 512; n0 = (nx - 8) * 64; }
  __shared__ __align__(16) __bf16 As[128][72];
  __shared__ __align__(16) __bf16 Bs[64][72];
  const int tid = threadIdx.x;
  const int wv = tid >> 6, lane = tid & 63, g4 = lane >> 4, l16 = lane & 15;
  const int m0 = blockIdx.y * 128;
  f32x4 acc[2][4];
#pragma unroll
  for (int m = 0; m < 2; ++m)
#pragma unroll
    for (int n = 0; n < 4; ++n) acc[m][n] = (f32x4){0.f, 0.f, 0.f, 0.f};
  for (int k0 = 0; k0 < K; k0 += 64) {
    __syncthreads();
    for (int idx = tid; idx < 1024; idx += 256) {
      const int r = idx >> 3, c8 = (idx & 7) << 3;
      *(uint4*)&As[r][c8] = *(const uint4*)&A[(size_t)(m0 + r) * K + k0 + c8];
    }
    for (int idx = tid; idx < 512; idx += 256) {
      const int r = idx >> 3, c8 = (idx & 7) << 3;
      *(uint4*)&Bs[r][c8] = *(const uint4*)&Bt[(size_t)(n0 + r) * K + k0 + c8];
    }
    __syncthreads();
#pragma unroll
    for (int t = 0; t < 2; ++t) {
      const bf16x8 a0 = *(const bf16x8*)&As[wv * 32 + l16][t * 32 + 8 * g4];
      const bf16x8 a1 = *(const bf16x8*)&As[wv * 32 + 16 + l16][t * 32 + 8 * g4];
#pragma unroll
      for (int n = 0; n < 4; ++n) {
        const bf16x8 b = *(const bf16x8*)&Bs[n * 16 + l16][t * 32 + 8 * g4];
        acc[0][n] = __builtin_amdgcn_mfma_f32_16x16x32_bf16(a0, b, acc[0][n], 0, 0, 0);
        acc[1][n] = __builtin_amdgcn_mfma_f32_16x16x32_bf16(a1, b, acc[1][n], 0, 0, 0);
      }
    }
  }
#pragma unroll
  for (int m = 0; m < 2; ++m)
#pragma unroll
    for (int n = 0; n < 4; ++n)
#pragma unroll
      for (int j = 0; j < 4; ++j)
        C[(size_t)(m0 + wv * 32 + m * 16 + g4 * 4 + j) * ldc + n0 + n * 16 + l16] =
            (__bf16)acc[m][n][j];
}

// ---------------- shared helpers ----------------
__device__ __forceinline__ void proj64(int tid, const __bf16 (*X)[72], __bf16 (*WP)[72],
                                       const __bf16* __restrict__ Wg,
                                       const float* __restrict__ bias, f32x4 acc[4]) {
  for (int idx = tid; idx < 512; idx += 256) {
    const int r = idx >> 3, c8 = (idx & 7) << 3;
    *(uint4*)&WP[r][c8] = *(const uint4*)&Wg[r * 64 + c8];
  }
  __syncthreads();
  const int lane = tid & 63, wv = tid >> 6, g4 = lane >> 4, l16 = lane & 15;
  const bf16x8 a0 = *(const bf16x8*)&X[wv * 16 + l16][8 * g4];
  const bf16x8 a1 = *(const bf16x8*)&X[wv * 16 + l16][32 + 8 * g4];
#pragma unroll
  for (int c = 0; c < 4; ++c) {
    f32x4 z = (f32x4){0.f, 0.f, 0.f, 0.f};
    const bf16x8 b0 = *(const bf16x8*)&WP[c * 16 + l16][8 * g4];
    const bf16x8 b1 = *(const bf16x8*)&WP[c * 16 + l16][32 + 8 * g4];
    z = __builtin_amdgcn_mfma_f32_16x16x32_bf16(a0, b0, z, 0, 0, 0);
    z = __builtin_amdgcn_mfma_f32_16x16x32_bf16(a1, b1, z, 0, 0, 0);
    const float bb = bias[c * 16 + l16];
    z[0] += bb; z[1] += bb; z[2] += bb; z[3] += bb;
    acc[c] = z;
  }
  __syncthreads();   // all waves done reading WP and X -> both may be overwritten
}

__device__ __forceinline__ void lnreg(f32x4 acc[4], const float gl[4], const float bl[4]) {
#pragma unroll
  for (int j = 0; j < 4; ++j) {
    float sm = acc[0][j] + acc[1][j] + acc[2][j] + acc[3][j];
    sm += __shfl_xor(sm, 1); sm += __shfl_xor(sm, 2);
    sm += __shfl_xor(sm, 4); sm += __shfl_xor(sm, 8);
    const float m = sm * (1.f / 64.f);
    float d[4], vs = 0.f;
#pragma unroll
    for (int c = 0; c < 4; ++c) { d[c] = acc[c][j] - m; vs += d[c] * d[c]; }
    vs += __shfl_xor(vs, 1); vs += __shfl_xor(vs, 2);
    vs += __shfl_xor(vs, 4); vs += __shfl_xor(vs, 8);
    const float rs = rsqrtf(vs * (1.f / 64.f) + 1e-5f);
#pragma unroll
    for (int c = 0; c < 4; ++c) acc[c][j] = d[c] * rs * gl[c] + bl[c];
  }
}

// ---------------- stage-1 per-window focus iteration (bf16 MFMA) ----------------
// QKV is bf16 (rope math still f32, via precomputed rope table rows 0..63).
// LDS aliasing: A0 = Xq then LN'd q; A1 = Xk then LN'd k; A2 = Xv then Vt (transposed v).
__global__ __launch_bounds__(256) void focus_win(
    int it, float sscale, const __bf16* __restrict__ QKV,
    __bf16* __restrict__ qst, __bf16* __restrict__ kst, __bf16* __restrict__ vst,
    __bf16* __restrict__ ast, __bf16* __restrict__ ybuf, float* __restrict__ dpart,
    const float2* __restrict__ rope,
    const __bf16* __restrict__ Wqht, const __bf16* __restrict__ Wkht,
    const __bf16* __restrict__ Wvht,
    const float* __restrict__ bq, const float* __restrict__ bk, const float* __restrict__ bv,
    const float* __restrict__ lng, const float* __restrict__ lnb) {
  __shared__ __align__(16) __bf16 A0[64][72], A1[64][72], A2[64][72];
  __shared__ __align__(16) __bf16 WP[64][72];
  __shared__ float red[256];
  __shared__ float flagsh;
  const int tid = threadIdx.x;
  const int bid = blockIdx.x;
  const int s = bid / 384, rem = bid % 384, w = rem >> 4, bh = rem & 15;
  const int b = bh >> 3, h = bh & 7;

  if (it == 2) {
    if (tid == 0) {
      const int g = s * 24 + w;
      float sum = 0.f;
      for (int i = 0; i < 16; ++i) sum += dpart[g * 16 + i];
      flagsh = (sum * (1.f / 65536.f) < 0.5f) ? 1.f : 0.f;
    }
    __syncthreads();
    if (flagsh > 0.5f) return;
  }

  const size_t sb = (size_t)bid * 4096;
  if (it == 0) {
    const int qrow0 = s * 3072 + b * 1536 + w * 64;
    const int krow0 = s * 3072 + b * 1536 + (w == 0 ? 0 : w * 64 - 8);
    for (int idx = tid; idx < 2048; idx += 256) {
      const int r = idx >> 5, j = idx & 31;
      const float2 rc = rope[r * 32 + j];
      const float sn = rc.x, cs = rc.y;
      const bf16x2 qp = *(const bf16x2*)&QKV[(size_t)(qrow0 + r) * 1536 + h * 64 + 2 * j];
      const float qr = (float)qp[0], qi = (float)qp[1];
      const float q0 = qr * cs - qi * sn;
      const float q1 = qr * sn + qi * cs;
      const bf16x2 qv = {(__bf16)q0, (__bf16)q1};
      *(bf16x2*)&A0[r][2 * j] = qv;
      *(bf16x2*)&qst[sb + r * 64 + 2 * j] = qv;
      const bf16x2 kp2 = *(const bf16x2*)&QKV[(size_t)(krow0 + r) * 1536 + 512 + h * 64 + 2 * j];
      const float kr = (float)kp2[0], ki = (float)kp2[1];
      A1[r][2 * j]     = (__bf16)(kr * cs - ki * sn);
      A1[r][2 * j + 1] = (__bf16)(kr * sn + ki * cs);
      const bf16x2 vp2 = *(const bf16x2*)&QKV[(size_t)(krow0 + r) * 1536 + 1024 + h * 64 + 2 * j];
      A2[r][2 * j] = vp2[0]; A2[r][2 * j + 1] = vp2[1];
    }
  } else {
    for (int idx = tid; idx < 512; idx += 256) {
      const int r = idx >> 3, c8 = (idx & 7) << 3;
      *(bf16x8*)&A0[r][c8] = *(const bf16x8*)&qst[sb + (size_t)r * 64 + c8];
      *(bf16x8*)&A1[r][c8] = *(const bf16x8*)&kst[sb + (size_t)r * 64 + c8];
      *(bf16x8*)&A2[r][c8] = *(const bf16x8*)&vst[sb + (size_t)r * 64 + c8];
    }
  }
  // (barrier inside first proj64 covers the staging writes)

  const int wv = tid >> 6, lane = tid & 63, g4 = lane >> 4, l16 = lane & 15;
  const int row = wv * 16 + g4 * 4;
  float gl[4], bl[4];
#pragma unroll
  for (int c = 0; c < 4; ++c) { gl[c] = lng[c * 16 + l16]; bl[c] = lnb[c * 16 + l16]; }

  f32x4 acc[4];
  // ---- qt = LN(A0 @ Wq + bq) -> back into A0 ----
  proj64(tid, A0, WP, Wqht, bq, acc);
  lnreg(acc, gl, bl);
#pragma unroll
  for (int c = 0; c < 4; ++c)
#pragma unroll
    for (int j = 0; j < 4; ++j) A0[row + j][c * 16 + l16] = (__bf16)acc[c][j];

  // ---- kt = A1 @ Wk + bk (store raw), LN -> back into A1 ----
  proj64(tid, A1, WP, Wkht, bk, acc);
  if (it <= 1)
#pragma unroll
    for (int c = 0; c < 4; ++c)
#pragma unroll
      for (int j = 0; j < 4; ++j) kst[sb + (size_t)(row + j) * 64 + c * 16 + l16] = (__bf16)acc[c][j];
  lnreg(acc, gl, bl);
#pragma unroll
  for (int c = 0; c < 4; ++c)
#pragma unroll
    for (int j = 0; j < 4; ++j) A1[row + j][c * 16 + l16] = (__bf16)acc[c][j];

  // ---- vt = A2 @ Wv + bv (store raw), transposed -> back into A2 ----
  proj64(tid, A2, WP, Wvht, bv, acc);
  if (it <= 1)
#pragma unroll
    for (int c = 0; c < 4; ++c)
#pragma unroll
      for (int j = 0; j < 4; ++j) vst[sb + (size_t)(row + j) * 64 + c * 16 + l16] = (__bf16)acc[c][j];
#pragma unroll
  for (int c = 0; c < 4; ++c) {
    bf16x4 pv = {(__bf16)acc[c][0], (__bf16)acc[c][1], (__bf16)acc[c][2], (__bf16)acc[c][3]};
    *(bf16x4*)&A2[c * 16 + l16][row] = pv;   // Vt[d][key]
  }
  __syncthreads();   // A0/A1/A2 new roles visible to all waves

  const bf16x8 aq0 = *(const bf16x8*)&A0[wv * 16 + l16][8 * g4];
  const bf16x8 aq1 = *(const bf16x8*)&A0[wv * 16 + l16][32 + 8 * g4];
  f32x4 sreg[4];
#pragma unroll
  for (int c = 0; c < 4; ++c) {
    f32x4 z = (f32x4){0.f, 0.f, 0.f, 0.f};
    const bf16x8 b0 = *(const bf16x8*)&A1[c * 16 + l16][8 * g4];
    const bf16x8 b1 = *(const bf16x8*)&A1[c * 16 + l16][32 + 8 * g4];
    z = __builtin_amdgcn_mfma_f32_16x16x32_bf16(aq0, b0, z, 0, 0, 0);
    z = __builtin_amdgcn_mfma_f32_16x16x32_bf16(aq1, b1, z, 0, 0, 0);
    sreg[c] = z * sscale;
  }
#pragma unroll
  for (int j = 0; j < 4; ++j) {
    float mx = fmaxf(fmaxf(sreg[0][j], sreg[1][j]), fmaxf(sreg[2][j], sreg[3][j]));
    mx = fmaxf(mx, __shfl_xor(mx, 1)); mx = fmaxf(mx, __shfl_xor(mx, 2));
    mx = fmaxf(mx, __shfl_xor(mx, 4)); mx = fmaxf(mx, __shfl_xor(mx, 8));
    float ps = 0.f;
#pragma unroll
    for (int c = 0; c < 4; ++c) { const float e = expf(sreg[c][j] - mx); sreg[c][j] = e; ps += e; }
    ps += __shfl_xor(ps, 1); ps += __shfl_xor(ps, 2);
    ps += __shfl_xor(ps, 4); ps += __shfl_xor(ps, 8);
    const float inv = 1.f / ps;
#pragma unroll
    for (int c = 0; c < 4; ++c) sreg[c][j] *= inv;
  }
#pragma unroll
  for (int c = 0; c < 4; ++c)
#pragma unroll
    for (int j = 0; j < 4; ++j) WP[row + j][c * 16 + l16] = (__bf16)sreg[c][j];
  const bf16x8 pa0 = *(const bf16x8*)&WP[wv * 16 + l16][8 * g4];
  const bf16x8 pa1 = *(const bf16x8*)&WP[wv * 16 + l16][32 + 8 * g4];
  f32x4 o[4];
#pragma unroll
  for (int dt = 0; dt < 4; ++dt) {
    f32x4 z = (f32x4){0.f, 0.f, 0.f, 0.f};
    const bf16x8 b0 = *(const bf16x8*)&A2[dt * 16 + l16][8 * g4];
    const bf16x8 b1 = *(const bf16x8*)&A2[dt * 16 + l16][32 + 8 * g4];
    z = __builtin_amdgcn_mfma_f32_16x16x32_bf16(pa0, b0, z, 0, 0, 0);
    z = __builtin_amdgcn_mfma_f32_16x16x32_bf16(pa1, b1, z, 0, 0, 0);
    o[dt] = z;
  }

  if (it == 0) {
#pragma unroll
    for (int dt = 0; dt < 4; ++dt)
#pragma unroll
      for (int j = 0; j < 4; ++j) {
        const size_t gi = sb + (size_t)(row + j) * 64 + dt * 16 + l16;
        const float a = o[dt][j];
        ast[gi] = (__bf16)a;
        qst[gi] = (__bf16)((float)qst[gi] + a);
      }
  } else if (it == 1) {
    float loc = 0.f;
#pragma unroll
    for (int dt = 0; dt < 4; ++dt)
#pragma unroll
      for (int j = 0; j < 4; ++j) {
        const size_t gi = sb + (size_t)(row + j) * 64 + dt * 16 + l16;
        const float a = o[dt][j];
        loc += fabsf(a - (float)ast[gi]);
        qst[gi] = (__bf16)((float)qst[gi] + a);
        ybuf[((size_t)((s * 2 + b) * 1536 + w * 64 + row + j)) * 512 + h * 64 + dt * 16 + l16] = (__bf16)a;
      }
    red[tid] = loc;
    __syncthreads();
    for (int o2 = 128; o2; o2 >>= 1) { if (tid < o2) red[tid] += red[tid + o2]; __syncthreads(); }
    if (tid == 0) dpart[bid] = red[0];
  } else {
#pragma unroll
    for (int dt = 0; dt < 4; ++dt)
#pragma unroll
      for (int j = 0; j < 4; ++j)
        ybuf[((size_t)((s * 2 + b) * 1536 + w * 64 + row + j)) * 512 + h * 64 + dt * 16 + l16] = (__bf16)o[dt][j];
  }
}

// ---------------- final-focus projection+LN, one op per block (q/k/v split) ----------------
// Grid (384, 3): x = chunk-unit (bh fastest -> XCD-local), y = op (0=q,1=k,2=v).
// it0 rope via precomputed table (bit-identical values).
__global__ __launch_bounds__(256) void fprojv(
    int it, float sscale, const float* __restrict__ flagp,
    const __bf16* __restrict__ QKV, const float2* __restrict__ rope,
    __bf16* __restrict__ curq, __bf16* __restrict__ kcur, __bf16* __restrict__ vcur,
    __bf16* __restrict__ qpack, __bf16* __restrict__ kpack, __bf16* __restrict__ vpack,
    const __bf16* __restrict__ Wqht, const __bf16* __restrict__ Wkht,
    const __bf16* __restrict__ Wvht,
    const float* __restrict__ bq, const float* __restrict__ bk, const float* __restrict__ bv,
    const float* __restrict__ lng, const float* __restrict__ lnb) {
  if (it == 2 && flagp[0] > 0.5f) return;
  __shared__ __align__(16) __bf16 X[64][72];
  __shared__ __align__(16) __bf16 Y[64][72];
  __shared__ __align__(16) __bf16 WP[64][72];
  const int tid = threadIdx.x;
  const int u = blockIdx.x, op = blockIdx.y;
  const int bh = u & 15, chunk = u >> 4;
  const size_t base = (size_t)bh * 98304 + (size_t)chunk * 4096;   // [t][64] element region

  if (it == 0) {
    const int t0 = chunk * 64;
    const int bb2 = bh >> 3, hh = bh & 7;
    if (op == 2) {
      // v: never roped -- pure bf16 vector copy from QKV cols [1024,1536)
      for (int idx = tid; idx < 512; idx += 256) {
        const int r = idx >> 3, c8 = (idx & 7) << 3;
        *(bf16x8*)&X[r][c8] =
            *(const bf16x8*)&QKV[(size_t)(bb2 * 1536 + t0 + r) * 1536 + 1024 + hh * 64 + c8];
      }
    } else {
      const int off = (op == 0) ? 0 : 512;
      for (int idx = tid; idx < 2048; idx += 256) {
        const int r = idx >> 5, j = idx & 31;
        const int t = t0 + r;
        const __bf16* src = QKV + (size_t)(bb2 * 1536 + t) * 1536 + off;
        const float2 rc = rope[t * 32 + j];
        const float sn = rc.x, cs = rc.y;
        const bf16x2 p2 = *(const bf16x2*)&src[hh * 64 + 2 * j];
        const float xr = (float)p2[0], xi = (float)p2[1];
        const float v0 = xr * cs - xi * sn;
        const float v1 = xr * sn + xi * cs;
        const bf16x2 pv = {(__bf16)v0, (__bf16)v1};
        *(bf16x2*)&X[r][2 * j] = pv;
        if (op == 0) *(bf16x2*)&curq[base + (size_t)r * 64 + 2 * j] = pv;
      }
    }
  } else {
    const __bf16* ch = (op == 0) ? curq : (op == 1) ? kcur : vcur;
    for (int idx = tid; idx < 512; idx += 256) {
      const int r = idx >> 3, c8 = (idx & 7) << 3;
      *(bf16x8*)&X[r][c8] = *(const bf16x8*)&ch[base + (size_t)r * 64 + c8];
    }
  }
  // (proj64's internal barrier covers the staging writes)

  const int wv = tid >> 6, lane = tid & 63, g4 = lane >> 4, l16 = lane & 15;
  const int row = wv * 16 + g4 * 4;

  const __bf16* Wg = (op == 0) ? Wqht : (op == 1) ? Wkht : Wvht;
  const float* bias = (op == 0) ? bq : (op == 1) ? bk : bv;
  f32x4 acc[4];
  proj64(tid, X, WP, Wg, bias, acc);

  if (op == 0) {
    float gl[4], bl[4];
#pragma unroll
    for (int c = 0; c < 4; ++c) { gl[c] = lng[c * 16 + l16]; bl[c] = lnb[c * 16 + l16]; }
    lnreg(acc, gl, bl);
#pragma unroll
    for (int c = 0; c < 4; ++c)
#pragma unroll
      for (int j = 0; j < 4; ++j) Y[row + j][c * 16 + l16] = (__bf16)(acc[c][j] * sscale);
    __syncthreads();
#pragma unroll
    for (int ii = 0; ii < 2; ++ii) {
      const int sg = tid * 2 + ii;               // 0..511
      const int g = sg >> 7, s = sg & 127;
      const int t = s >> 6, g4p = (s >> 4) & 3, l16p = s & 15;
      bf16x8 pv = *(const bf16x8*)&Y[g * 16 + l16p][t * 32 + 8 * g4p];
      *(bf16x8*)&qpack[base + (size_t)g * 1024 + (size_t)s * 8] = pv;
    }
  } else if (op == 1) {
#pragma unroll
    for (int c = 0; c < 4; ++c)
#pragma unroll
      for (int j = 0; j < 4; ++j)
        kcur[base + (size_t)(row + j) * 64 + c * 16 + l16] = (__bf16)acc[c][j];
    float gl[4], bl[4];
#pragma unroll
    for (int c = 0; c < 4; ++c) { gl[c] = lng[c * 16 + l16]; bl[c] = lnb[c * 16 + l16]; }
    lnreg(acc, gl, bl);
#pragma unroll
    for (int c = 0; c < 4; ++c)
#pragma unroll
      for (int j = 0; j < 4; ++j) Y[row + j][c * 16 + l16] = (__bf16)acc[c][j];
    __syncthreads();
#pragma unroll
    for (int ii = 0; ii < 2; ++ii) {
      const int sg = tid * 2 + ii;
      const int g = sg >> 7, s = sg & 127;
      const int t = s >> 6, g4p = (s >> 4) & 3, l16p = s & 15;
      bf16x8 pv = *(const bf16x8*)&Y[g * 16 + l16p][t * 32 + 8 * g4p];
      *(bf16x8*)&kpack[base + (size_t)g * 1024 + (size_t)s * 8] = pv;
    }
  } else {
#pragma unroll
    for (int c = 0; c < 4; ++c)
#pragma unroll
      for (int j = 0; j < 4; ++j) {
        vcur[base + (size_t)(row + j) * 64 + c * 16 + l16] = (__bf16)acc[c][j];
        Y[row + j][c * 16 + l16] = (__bf16)acc[c][j];
      }
    __syncthreads();
#pragma unroll
    for (int ii = 0; ii < 2; ++ii) {
      const int sg = tid * 2 + ii;               // 0..511 = dt*128 + s
      const int dt = sg >> 7, s = sg & 127;
      const int t = s >> 6, g4p = (s >> 4) & 3, l16p = s & 15;
      bf16x8 pv;
#pragma unroll
      for (int j = 0; j < 8; ++j)
        pv[j] = Y[t * 32 + 8 * g4p + j][dt * 16 + l16p];
      *(bf16x8*)&vpack[base + (size_t)sg * 8] = pv;
    }
  }
}

// ---------------- final-focus flash attention: 16 q-rows/block (1 strip), 4-way k-split,
// no-max softmax. Grid 1536: bid = qc*16 + bh (96 q-chunks, bh fastest for XCD-local L2).
// (256,3): natural VGPR, no spill. Pipelined k-loop (R26). R30: s_setprio(1) around MFMA
// clusters -- waves here are phase-independent (private k-quarters, no barrier until the
// merge), the proven-positive setprio regime (learn_hip m191: +4-7% attn).
__global__ __launch_bounds__(256, 3) void fattn(
    int it,
    const __bf16* __restrict__ qpack, const __bf16* __restrict__ kpack,
    const __bf16* __restrict__ vpack,
    __bf16* __restrict__ Rout, __bf16* __restrict__ aprev, __bf16* __restrict__ curq,
    float* __restrict__ dpart, const float* __restrict__ flagp) {
  if (it == 2 && flagp[0] > 0.5f) return;
  __shared__ __align__(16) __bf16 Pl[4][16][72]; // per-wave P transpose strip
  __shared__ float Ob[4][16][65];                // per-wave O-numerator partials
  __shared__ float Ll[4][16];                    // per-wave l partials
  __shared__ float redm[4];
  const int tid = threadIdx.x;
  const int wv = tid >> 6, lane = tid & 63;
  const int g4 = lane >> 4, l16 = lane & 15;
  const int bid = blockIdx.x;
  const int bh = bid & 15, qc = bid >> 4;          // qc in 0..95
  const int bb2 = bh >> 3, hh = bh & 7;            // batch, head for reorder write
  const size_t base = (size_t)bh * (1536 * 64);
  const __bf16* qp = qpack + base;
  const __bf16* kp = kpack + base;
  const __bf16* vp = vpack + base;
  const int q0 = qc * 16;

  bf16x8 aq[2];
#pragma unroll
  for (int t = 0; t < 2; ++t)
    aq[t] = *(const bf16x8*)&qp[(size_t)qc * 1024 + (size_t)(t * 64 + lane) * 8];

  f32x4 oacc[4];
#pragma unroll
  for (int dt = 0; dt < 4; ++dt) oacc[dt] = (f32x4){0.f, 0.f, 0.f, 0.f};
  float lsum[4] = {0.f, 0.f, 0.f, 0.f};

  const int kbeg = wv * 384, kend = kbeg + 384;
  // prologue: first tile's K fragments
  bf16x8 bk[4][2];
#pragma unroll
  for (int c = 0; c < 4; ++c)
#pragma unroll
    for (int t = 0; t < 2; ++t)
      bk[c][t] = *(const bf16x8*)&kp[(size_t)((kbeg >> 4) + c) * 1024 + (size_t)(t * 64 + lane) * 8];

  for (int k0 = kbeg; k0 < kend; k0 += 64) {
    // prefetch next tile's K fragments (latency hidden under this tile's compute)
    const int k1 = k0 + 64;
    bf16x8 bkn[4][2];
    if (k1 < kend) {
#pragma unroll
      for (int c = 0; c < 4; ++c)
#pragma unroll
        for (int t = 0; t < 2; ++t)
          bkn[c][t] = *(const bf16x8*)&kp[(size_t)((k1 >> 4) + c) * 1024 + (size_t)(t * 64 + lane) * 8];
    }

    // QK^T MFMAs (setprio: favor the matrix pipe while other waves issue loads)
    f32x4 s[4];
    __builtin_amdgcn_s_setprio(1);
#pragma unroll
    for (int c = 0; c < 4; ++c) {
      f32x4 a = (f32x4){0.f, 0.f, 0.f, 0.f};
      a = __builtin_amdgcn_mfma_f32_16x16x32_bf16(aq[0], bk[c][0], a, 0, 0, 0);
      a = __builtin_amdgcn_mfma_f32_16x16x32_bf16(aq[1], bk[c][1], a, 0, 0, 0);
      s[c] = a;   // Q pre-scaled by sscale
    }
    __builtin_amdgcn_s_setprio(0);

    // V fragments: batch-issued so their latency hides under exp + LDS roundtrip
    bf16x8 vv[4][2];
#pragma unroll
    for (int dt = 0; dt < 4; ++dt) {
      const size_t vb = (size_t)((k0 >> 6) * 4 + dt) * 1024;
      vv[dt][0] = *(const bf16x8*)&vp[vb + (size_t)lane * 8];
      vv[dt][1] = *(const bf16x8*)&vp[vb + (size_t)(64 + lane) * 8];
    }

    // no-max softmax: p = exp(s); per-lane partial l (cross-lane reduce deferred)
#pragma unroll
    for (int c = 0; c < 4; ++c)
#pragma unroll
      for (int j = 0; j < 4; ++j) {
        const float p = __expf(s[c][j]);
        s[c][j] = p;
        lsum[j] += p;
      }
    // P C-layout -> A-layout via per-wave LDS strip
#pragma unroll
    for (int c = 0; c < 4; ++c)
#pragma unroll
      for (int j = 0; j < 4; ++j)
        Pl[wv][g4 * 4 + j][c * 16 + l16] = (__bf16)s[c][j];
    bf16x8 pa[2];
#pragma unroll
    for (int t = 0; t < 2; ++t)
      pa[t] = *(const bf16x8*)&Pl[wv][l16][t * 32 + 8 * g4];

    // PV MFMAs consume the prefetched V fragments
    __builtin_amdgcn_s_setprio(1);
#pragma unroll
    for (int dt = 0; dt < 4; ++dt) {
      oacc[dt] = __builtin_amdgcn_mfma_f32_16x16x32_bf16(pa[0], vv[dt][0], oacc[dt], 0, 0, 0);
      oacc[dt] = __builtin_amdgcn_mfma_f32_16x16x32_bf16(pa[1], vv[dt][1], oacc[dt], 0, 0, 0);
    }
    __builtin_amdgcn_s_setprio(0);

    if (k1 < kend) {
#pragma unroll
      for (int c = 0; c < 4; ++c) {
        bk[c][0] = bkn[c][0];
        bk[c][1] = bkn[c][1];
      }
    }
  }

  // one deferred cross-lane l reduction
#pragma unroll
  for (int j = 0; j < 4; ++j) {
    lsum[j] += __shfl_xor(lsum[j], 1);
    lsum[j] += __shfl_xor(lsum[j], 2);
    lsum[j] += __shfl_xor(lsum[j], 4);
    lsum[j] += __shfl_xor(lsum[j], 8);
  }
  if (l16 == 0) {
#pragma unroll
    for (int j = 0; j < 4; ++j) Ll[wv][g4 * 4 + j] = lsum[j];
  }
#pragma unroll
  for (int dt = 0; dt < 4; ++dt)
#pragma unroll
    for (int j = 0; j < 4; ++j)
      Ob[wv][g4 * 4 + j][dt * 16 + l16] = oacc[dt][j];
  __syncthreads();

  // merge (pure sums): each wave merges 4 rows, lane = column
  float loc = 0.f;
  const int col = lane;
#pragma unroll
  for (int rr = 0; rr < 4; ++rr) {
    const int r = wv * 4 + rr;
    const float L = Ll[0][r] + Ll[1][r] + Ll[2][r] + Ll[3][r];
    const float o = (Ob[0][r][col] + Ob[1][r][col] +
                     Ob[2][r][col] + Ob[3][r][col]) / L;
    const size_t gi = base + (size_t)(q0 + r) * 64 + col;
    if (it == 1) loc += fabsf(o - (float)aprev[gi]);
    if (it > 0)   // final output path: reordered bf16 GEMM input (a0 never final)
      Rout[(size_t)(bb2 * 1536 + q0 + r) * 512 + hh * 64 + col] = (__bf16)o;
    if (it == 0) { aprev[gi] = (__bf16)o; curq[gi] = (__bf16)((float)curq[gi] + o); }
    else if (it == 1) curq[gi] = (__bf16)((float)curq[gi] + o);  // aprev never read after it1
  }
  if (it == 1) {
    for (int o2 = 32; o2; o2 >>= 1) loc += __shfl_xor(loc, o2, 64);
    if (lane == 0) redm[wv] = loc;
    __syncthreads();
    if (tid == 0) dpart[bid] = redm[0] + redm[1] + redm[2] + redm[3];
  }
}

__global__ void fdec(const float* __restrict__ dpart, float* __restrict__ flagp) {
  const int l = threadIdx.x;   // 64 threads; 1536 partials
  float s = 0.f;
  for (int i = 0; i < 24; ++i) s += dpart[l * 24 + i];
  for (int o = 32; o; o >>= 1) s += __shfl_xor(s, o, 64);
  if (l == 0) flagp[0] = (s * (1.f / 1572864.f) < 0.5f) ? 1.f : 0.f;
}

// ---------------- launch ----------------
extern "C" void kernel_launch(void* const* d_in, const int* in_sizes, int n_in,
                              void* d_out, int out_size, void* d_ws, size_t ws_size,
                              hipStream_t stream) {
  const float* x     = (const float*)d_in[0];
  const float* xa    = (const float*)d_in[1];
  const float* Wq    = (const float*)d_in[2];
  const float* Wkv   = (const float*)d_in[3];
  const float* Wo    = (const float*)d_in[4];
  const float* lna_g = (const float*)d_in[5];
  const float* lna_b = (const float*)d_in[6];
  const float* lnb_g = (const float*)d_in[7];
  const float* lnb_b = (const float*)d_in[8];
  const float* Wq_hd = (const float*)d_in[9];
  const float* bq_hd = (const float*)d_in[10];
  const float* Wk_hd = (const float*)d_in[11];
  const float* bk_hd = (const float*)d_in[12];
  const float* Wv_hd = (const float*)d_in[13];
  const float* bv_hd = (const float*)d_in[14];
  const float* theta = (const float*)d_in[15];
  float* out = (float*)d_out;
  float* ws = (float*)d_ws;
  if (ws_size < (size_t)WS_FLOATS * sizeof(float)) return;

  float* freq = ws + OFF_FREQ;
  float2* rope = (float2*)(ws + OFF_RT);
  __bf16* lnAb = (__bf16*)(ws + OFF_LNA);
  __bf16* Wallt = (__bf16*)(ws + OFF_WALL);
  __bf16* Wot  = (__bf16*)(ws + OFF_WOT);
  __bf16* Wqht = (__bf16*)(ws + OFF_WQH);
  __bf16* Wkht = (__bf16*)(ws + OFF_WKH);
  __bf16* Wvht = (__bf16*)(ws + OFF_WVH);
  __bf16* QKV = (__bf16*)(ws + OFF_QKV);
  __bf16* ybuf = (__bf16*)(ws + OFF_YBUF);
  __bf16* qst = (__bf16*)(ws + OFF_QST);
  __bf16* kst = (__bf16*)(ws + OFF_KST);
  __bf16* vst = (__bf16*)(ws + OFF_VST);
  __bf16* ast = (__bf16*)(ws + OFF_AST);
  __bf16* curq = (__bf16*)(ws + OFF_CURQ);
  __bf16* kcur = (__bf16*)(ws + OFF_KCUR);
  __bf16* vcur = (__bf16*)(ws + OFF_VCUR);
  __bf16* apr  = (__bf16*)(ws + OFF_APR);
  float* dp1  = ws + OFF_DP1;
  float* dpf2 = ws + OFF_DPF2;   // 1536 fattn diff partials
  float* flg  = ws + OFF_FLAG;
  __bf16* qpack = (__bf16*)(ws + OFF_QPK);
  __bf16* kpack = (__bf16*)(ws + OFF_KPK);
  __bf16* vpack = (__bf16*)(ws + OFF_VPK);

  const float sc[3] = {0.125f,
                       (float)(0.125 * sqrt(1.0 / 0.995)),
                       (float)(0.125 * sqrt(1.0 / 0.99))};

  conv_all<<<452, 256, 0, stream>>>(theta, Wq, Wkv, Wo, Wq_hd, Wk_hd, Wv_hd,
                                    freq, rope, Wallt, Wot, Wqht, Wkht, Wvht);

  // ---- stage 1: both slides ----
  ln512w<<<1536, 256, 0, stream>>>(x, xa, lna_g, lna_b, lnAb);
  gemm_bfb<<<dim3(24, 48), 256, 0, stream>>>(lnAb, Wallt, QKV, 1536, 512);
  for (int it = 0; it < 3; ++it)
    focus_win<<<768, 256, 0, stream>>>(it, sc[it], QKV, qst, kst, vst, ast, ybuf, dp1,
                                       rope, Wqht, Wkht, Wvht, bq_hd, bk_hd, bv_hd,
                                       lnb_g, lnb_b);

  // ---- final focus ----
  ln512bw<<<1536, 256, 0, stream>>>(ybuf, lna_g, lna_b, lnAb);
  gemm_ff<<<dim3(24, 24), 256, 0, stream>>>(lnAb, Wallt, QKV);

  for (int it = 0; it < 3; ++it) {
    fprojv<<<dim3(384, 3), 256, 0, stream>>>(it, sc[it], flg, QKV, rope, curq, kcur, vcur,
                                             qpack, kpack, vpack,
                                             Wqht, Wkht, Wvht, bq_hd, bk_hd, bv_hd,
                                             lnb_g, lnb_b);
    fattn<<<1536, 256, 0, stream>>>(it, qpack, kpack, vpack,
                                    lnAb, apr, curq, dpf2, flg);
    if (it == 1) fdec<<<1, 64, 0, stream>>>(dpf2, flg);
  }

  // ---- output projection (fattn wrote reordered bf16 R directly into lnAb) ----
  gemm_bf<<<dim3(8, 24), 256, 0, stream>>>(lnAb, Wot, out, 512, 512);
}